// Round 2
// baseline (1474.004 us; speedup 1.0000x reference)
//
#include <hip/hip_runtime.h>
#include <hip/hip_bf16.h>
#include <hip/hip_fp16.h>
#include <math.h>

#define N_NODES 50000
#define N_EDGES 800000
#define NHEADS  4
#define NEG_SLOPE 0.2f

typedef __attribute__((ext_vector_type(8))) short short8v;  // 8 bf16
typedef __attribute__((ext_vector_type(4))) float f32x4;

__device__ inline ushort f2bf(float f) {  // RNE float->bf16 bits
  uint u = __float_as_uint(f);
  u += 0x7FFFu + ((u >> 16) & 1u);
  return (ushort)(u >> 16);
}

// ---------------------------------------------------------------------------
// split fp32 -> (hi, lo) bf16 pair, elementwise, row-major passthrough
// ---------------------------------------------------------------------------
__global__ void split_kernel(const float* __restrict__ in, ushort* __restrict__ hi,
                             ushort* __restrict__ lo, int n) {
  int i = blockIdx.x * blockDim.x + threadIdx.x;
  int s = gridDim.x * blockDim.x;
  for (; i < n; i += s) {
    float v = in[i];
    ushort h = f2bf(v);
    float hf = __uint_as_float((uint)h << 16);
    hi[i] = h;
    lo[i] = f2bf(v - hf);
  }
}

// split + transpose: W[K][N] -> Bt_hi/lo [N][K]
__global__ void splitT_kernel(const float* __restrict__ W, ushort* __restrict__ hi,
                              ushort* __restrict__ lo, int kshift, int N, int n) {
  int i = blockIdx.x * blockDim.x + threadIdx.x;
  if (i >= n) return;
  int K = 1 << kshift;
  int nn = i >> kshift, k = i & (K - 1);
  float v = W[(size_t)k * N + nn];
  ushort h = f2bf(v);
  float hf = __uint_as_float((uint)h << 16);
  hi[i] = h;
  lo[i] = f2bf(v - hf);
}

// ---------------------------------------------------------------------------
// split-bf16 MFMA GEMM: C[M,N] = A[M,K]@B[K,N] via Ahi*Bhi+Ahi*Blo+Alo*Bhi.
// Bt is [N][K]. Block = 4 waves, tile 64x64; wave w owns rows [16w,16w+16).
// Epilogue: writes h16 (fp16) and accumulates a_s/a_d = h . asrc/adst
// ---------------------------------------------------------------------------
__global__ __launch_bounds__(256) void gemm_mfma_kernel(
    const ushort* __restrict__ Ahi, const ushort* __restrict__ Alo,
    const ushort* __restrict__ Bthi, const ushort* __restrict__ Btlo,
    __half* __restrict__ h16, const float* __restrict__ asrc,
    const float* __restrict__ adst, float* __restrict__ a_s,
    float* __restrict__ a_d, int M, int K, int N, int Cph) {
  int tid = threadIdx.x;
  int w = tid >> 6, lane = tid & 63;
  int r16 = lane & 15, kgrp = lane >> 4;
  int bm = blockIdx.y * 64, bn = blockIdx.x * 64;
  int arow = bm + w * 16 + r16;
  int arow_c = (arow < M) ? arow : (M - 1);
  const ushort* aph = Ahi + (size_t)arow_c * K + kgrp * 8;
  const ushort* apl = Alo + (size_t)arow_c * K + kgrp * 8;
  const ushort* bph = Bthi + (size_t)(bn + r16) * K + kgrp * 8;
  const ushort* bpl = Btlo + (size_t)(bn + r16) * K + kgrp * 8;

  f32x4 acc[4] = {};
  for (int k0 = 0; k0 < K; k0 += 32) {
    short8v ah = *(const short8v*)(aph + k0);
    short8v al = *(const short8v*)(apl + k0);
#pragma unroll
    for (int j = 0; j < 4; ++j) {
      short8v bh = *(const short8v*)(bph + (size_t)j * 16 * K + k0);
      short8v bl = *(const short8v*)(bpl + (size_t)j * 16 * K + k0);
      acc[j] = __builtin_amdgcn_mfma_f32_16x16x32_bf16(ah, bh, acc[j], 0, 0, 0);
      acc[j] = __builtin_amdgcn_mfma_f32_16x16x32_bf16(ah, bl, acc[j], 0, 0, 0);
      acc[j] = __builtin_amdgcn_mfma_f32_16x16x32_bf16(al, bh, acc[j], 0, 0, 0);
    }
  }

  int hd = bn / Cph;
#pragma unroll
  for (int r = 0; r < 4; ++r) {
    int row = bm + w * 16 + 4 * kgrp + r;
    bool ok = row < M;
    float ps = 0.f, pd = 0.f;
#pragma unroll
    for (int j = 0; j < 4; ++j) {
      float val = acc[j][r];
      int col = bn + 16 * j + r16;
      if (ok) h16[(size_t)row * N + col] = __float2half(val);
      ps += val * asrc[col];
      pd += val * adst[col];
    }
#pragma unroll
    for (int o = 8; o >= 1; o >>= 1) {
      ps += __shfl_xor(ps, o);
      pd += __shfl_xor(pd, o);
    }
    if (r16 == 0 && ok) {
      atomicAdd(&a_s[row * NHEADS + hd], ps);
      atomicAdd(&a_d[row * NHEADS + hd], pd);
    }
  }
}

// ---------------------------------------------------------------------------
// edge_attr column sums (for mean)
// ---------------------------------------------------------------------------
__global__ void ea_colsum_kernel(const float* __restrict__ ea,
                                 float* __restrict__ sums, int E) {
  int tid = threadIdx.x;
  int col = tid & 15;
  float s = 0.f;
  for (int r = blockIdx.x * 16 + (tid >> 4); r < E; r += gridDim.x * 16)
    s += ea[(size_t)r * 16 + col];
  __shared__ float red[256];
  red[tid] = s;
  __syncthreads();
  for (int off = 128; off >= 16; off >>= 1) {
    if (tid < off) red[tid] += red[tid + off];
    __syncthreads();
  }
  if (tid < 16) atomicAdd(&sums[tid], red[tid]);
}

// ---------------------------------------------------------------------------
// wvec[l][k][h] = sum_c We_l[k, h*C+c] * ae_l[h,c];  ae_self[l][h] from mean ea
// ---------------------------------------------------------------------------
__global__ void wvec_kernel(const float* __restrict__ We0, const float* __restrict__ ae0,
                            const float* __restrict__ We1, const float* __restrict__ ae1,
                            const float* __restrict__ We2, const float* __restrict__ ae2,
                            const float* __restrict__ ea_sum,
                            float* __restrict__ wvec, float* __restrict__ ae_self) {
  __shared__ float sw[192];
  int tid = threadIdx.x;
  if (tid < 192) {
    int l = tid >> 6, rem = tid & 63, k = rem >> 2, hd = rem & 3;
    int C = (l == 2) ? 128 : 64;
    const float* We = (l == 0) ? We0 : (l == 1) ? We1 : We2;
    const float* ae = (l == 0) ? ae0 : (l == 1) ? ae1 : ae2;
    float s = 0.f;
    for (int c = 0; c < C; ++c) s += We[(size_t)k * (4 * C) + hd * C + c] * ae[hd * C + c];
    sw[tid] = s;
    wvec[tid] = s;  // layout: l*64 + k*4 + hd
  }
  __syncthreads();
  if (tid < 12) {
    int l = tid >> 2, hd = tid & 3;
    const float invE = 1.0f / (float)N_EDGES;
    float s = 0.f;
    for (int k = 0; k < 16; ++k) s += ea_sum[k] * invE * sw[l * 64 + k * 4 + hd];
    ae_self[tid] = s;
  }
}

// ---------------------------------------------------------------------------
// a_e[e][h] = sum_k ea[e,k] * wvec[k,h]
// ---------------------------------------------------------------------------
__global__ void ae_kernel(const float* __restrict__ ea, const float* __restrict__ wv,
                          float* __restrict__ a_e, int E) {
  int i = blockIdx.x * blockDim.x + threadIdx.x;
  int stride = gridDim.x * blockDim.x;
  for (int e = i; e < E; e += stride) {
    const float* row = ea + (size_t)e * 16;
    float s0 = 0, s1 = 0, s2 = 0, s3 = 0;
#pragma unroll
    for (int k = 0; k < 16; ++k) {
      float v = row[k];
      s0 += v * wv[k * 4 + 0];
      s1 += v * wv[k * 4 + 1];
      s2 += v * wv[k * 4 + 2];
      s3 += v * wv[k * 4 + 3];
    }
    *(float4*)(a_e + (size_t)e * 4) = make_float4(s0, s1, s2, s3);
  }
}

// ---------------------------------------------------------------------------
// CSR build
// ---------------------------------------------------------------------------
__global__ void deg_init_kernel(int* deg, int n) {
  int i = blockIdx.x * blockDim.x + threadIdx.x;
  if (i < n) deg[i] = 1;  // self-loop
}
__global__ void deg_count_kernel(const int* __restrict__ dst, int* deg, int E) {
  int i = blockIdx.x * blockDim.x + threadIdx.x;
  int s = gridDim.x * blockDim.x;
  for (; i < E; i += s) atomicAdd(&deg[dst[i]], 1);
}
__global__ void scan_kernel(const int* __restrict__ deg, int* __restrict__ offsets,
                            int* __restrict__ cursor, int n) {
  __shared__ int sums[1024];
  int tid = threadIdx.x;
  int chunk = (n + 1023) >> 10;
  int lo = tid * chunk; if (lo > n) lo = n;
  int hi = lo + chunk;  if (hi > n) hi = n;
  int s = 0;
  for (int i = lo; i < hi; ++i) s += deg[i];
  sums[tid] = s;
  __syncthreads();
  for (int d = 1; d < 1024; d <<= 1) {
    int v = (tid >= d) ? sums[tid - d] : 0;
    __syncthreads();
    sums[tid] += v;
    __syncthreads();
  }
  int run = (tid > 0) ? sums[tid - 1] : 0;
  for (int i = lo; i < hi; ++i) {
    offsets[i] = run;
    cursor[i] = run;
    run += deg[i];
  }
  if (tid == 0) offsets[n] = sums[1023];
}
__global__ void scatter_kernel(const int* __restrict__ src, const int* __restrict__ dst,
                               int* cursor, int* __restrict__ csr_src,
                               int* __restrict__ csr_eid, int E, int n) {
  int i = blockIdx.x * blockDim.x + threadIdx.x;
  int s = gridDim.x * blockDim.x;
  int tot = E + n;
  for (; i < tot; i += s) {
    int ss, dd, eid;
    if (i < E) { ss = src[i]; dd = dst[i]; eid = i; }
    else       { ss = i - E; dd = ss;     eid = E; }   // self-loop sentinel
    int pos = atomicAdd(&cursor[dd], 1);
    csr_src[pos] = ss;
    csr_eid[pos] = eid;
  }
}

// ---------------------------------------------------------------------------
// aggregation: per dst node softmax over incoming edges + weighted sum of h[src]
// h gathered in fp16.  block = 1 node, wave = 1 head, lanes = channels
// MODE 0: concat + bias + ELU (layers 0,1, C=64)
// MODE 1: head-mean + bias     (layer 2,  C=128)
// ---------------------------------------------------------------------------
template <int C, int MODE>
__global__ __launch_bounds__(256) void agg_kernel(
    const __half* __restrict__ h, const float* __restrict__ a_s,
    const float* __restrict__ a_d, const float* __restrict__ a_e,
    const float* __restrict__ ae_self, const int* __restrict__ offsets,
    const int* __restrict__ csr_src, const int* __restrict__ csr_eid,
    const float* __restrict__ bias, float* __restrict__ y) {
  constexpr int HC = NHEADS * C;
  int node = blockIdx.x;
  int hd = threadIdx.x >> 6, l = threadIdx.x & 63;
  int beg = offsets[node], end = offsets[node + 1];
  float a_dn = a_d[node * NHEADS + hd];
  float aes = ae_self[hd];
  float acc0 = 0.f, acc1 = 0.f, denom = 0.f;

  if (end - beg <= 64) {
    int j = beg + l;
    bool valid = j < end;
    int s = 0;
    float al = -1e30f;
    if (valid) {
      s = csr_src[j];
      int eid = csr_eid[j];
      float aev = (eid < N_EDGES) ? a_e[(size_t)eid * NHEADS + hd] : aes;
      float v = a_s[s * NHEADS + hd] + a_dn + aev;
      al = (v > 0.f) ? v : NEG_SLOPE * v;
    }
    float m = al;
#pragma unroll
    for (int o = 32; o >= 1; o >>= 1) m = fmaxf(m, __shfl_xor(m, o));
    float ex = valid ? __expf(al - m) : 0.f;
    denom = ex;
#pragma unroll
    for (int o = 32; o >= 1; o >>= 1) denom += __shfl_xor(denom, o);
    int cnt = end - beg;
    for (int t = 0; t < cnt; ++t) {
      float w = __shfl(ex, t);
      int ss = __shfl(s, t);
      const __half* hp = h + (size_t)ss * HC + hd * C;
      acc0 += w * __half2float(hp[l]);
      if (C == 128) acc1 += w * __half2float(hp[64 + l]);
    }
  } else {
    float m = -1e30f;
    for (int j0 = beg; j0 < end; j0 += 64) {
      int j = j0 + l;
      float al = -1e30f;
      if (j < end) {
        int s = csr_src[j];
        int eid = csr_eid[j];
        float aev = (eid < N_EDGES) ? a_e[(size_t)eid * NHEADS + hd] : aes;
        float v = a_s[s * NHEADS + hd] + a_dn + aev;
        al = (v > 0.f) ? v : NEG_SLOPE * v;
      }
      m = fmaxf(m, al);
    }
#pragma unroll
    for (int o = 32; o >= 1; o >>= 1) m = fmaxf(m, __shfl_xor(m, o));
    for (int j0 = beg; j0 < end; j0 += 64) {
      int j = j0 + l;
      int s = 0;
      float ex = 0.f;
      if (j < end) {
        s = csr_src[j];
        int eid = csr_eid[j];
        float aev = (eid < N_EDGES) ? a_e[(size_t)eid * NHEADS + hd] : aes;
        float v = a_s[s * NHEADS + hd] + a_dn + aev;
        float al = (v > 0.f) ? v : NEG_SLOPE * v;
        ex = __expf(al - m);
      }
      denom += ex;
      int cnt = min(64, end - j0);
      for (int t = 0; t < cnt; ++t) {
        float w = __shfl(ex, t);
        int ss = __shfl(s, t);
        const __half* hp = h + (size_t)ss * HC + hd * C;
        acc0 += w * __half2float(hp[l]);
        if (C == 128) acc1 += w * __half2float(hp[64 + l]);
      }
    }
#pragma unroll
    for (int o = 32; o >= 1; o >>= 1) denom += __shfl_xor(denom, o);
  }

  float inv = 1.0f / (denom + 1e-16f);
  float v0 = acc0 * inv;
  if (MODE == 0) {
    float o = v0 + bias[hd * C + l];
    y[(size_t)node * HC + hd * C + l] = (o > 0.f) ? o : (__expf(o) - 1.f);
  } else {
    float v1 = acc1 * inv;
    __shared__ float red[NHEADS][128];
    red[hd][l] = v0;
    red[hd][64 + l] = v1;
    __syncthreads();
    if (hd == 0) {
#pragma unroll
      for (int q = 0; q < 2; ++q) {
        int c = l + q * 64;
        float sum = (red[0][c] + red[1][c] + red[2][c] + red[3][c]) * 0.25f + bias[c];
        y[(size_t)node * 128 + c] = sum;
      }
    }
  }
}

// ---------------------------------------------------------------------------
// global mean pool
// ---------------------------------------------------------------------------
__global__ void pool_kernel(const float* __restrict__ y, const int* __restrict__ batch,
                            float* __restrict__ pool, float* __restrict__ cnt, int n) {
  int n0 = blockIdx.x * 256;
  if (n0 >= n) return;
  int n1 = min(n0 + 256, n);
  int c = threadIdx.x;  // 128 threads
  float accum = 0.f;
  int cur = batch[n0];
  int cn = 0;
  for (int nd = n0; nd < n1; ++nd) {
    int g = batch[nd];
    if (g != cur) {
      atomicAdd(&pool[cur * 128 + c], accum);
      if (c == 0) atomicAdd(&cnt[cur], (float)cn);
      accum = 0.f; cn = 0; cur = g;
    }
    accum += y[(size_t)nd * 128 + c];
    cn++;
  }
  atomicAdd(&pool[cur * 128 + c], accum);
  if (c == 0) atomicAdd(&cnt[cur], (float)cn);
}
__global__ void finalize_kernel(const float* __restrict__ pool,
                                const float* __restrict__ cnt, float* __restrict__ out) {
  int i = blockIdx.x * blockDim.x + threadIdx.x;
  if (i < 64 * 128) out[i] = pool[i] / fmaxf(cnt[i >> 7], 1.f);
}

// ---------------------------------------------------------------------------
extern "C" void kernel_launch(void* const* d_in, const int* in_sizes, int n_in,
                              void* d_out, int out_size, void* d_ws, size_t ws_size,
                              hipStream_t stream) {
  const float* x = (const float*)d_in[0];
  const int* ei = (const int*)d_in[1];
  const float* ea = (const float*)d_in[2];
  const int* batch = (const int*)d_in[3];
  const float* W[3]    = {(const float*)d_in[4],  (const float*)d_in[10], (const float*)d_in[16]};
  const float* asrc[3] = {(const float*)d_in[5],  (const float*)d_in[11], (const float*)d_in[17]};
  const float* adst[3] = {(const float*)d_in[6],  (const float*)d_in[12], (const float*)d_in[18]};
  const float* Wep[3]  = {(const float*)d_in[7],  (const float*)d_in[13], (const float*)d_in[19]};
  const float* aep[3]  = {(const float*)d_in[8],  (const float*)d_in[14], (const float*)d_in[20]};
  const float* bp[3]   = {(const float*)d_in[9],  (const float*)d_in[15], (const float*)d_in[21]};

  char* ws = (char*)d_ws;
  size_t off = 0;
  auto take = [&](size_t bytes) -> void* {
    void* p = ws + off;
    off = (off + bytes + 255) & ~(size_t)255;
    return p;
  };
  float* zero_region = (float*)take((16 + 8192 + 64) * 4);
  float* ea_sum = zero_region;
  float* pool   = zero_region + 16;
  float* cnt    = zero_region + 16 + 8192;
  float* wvec    = (float*)take(192 * 4);
  float* ae_self = (float*)take(12 * 4);
  int* deg     = (int*)take((size_t)N_NODES * 4);
  int* offsets = (int*)take(((size_t)N_NODES + 1) * 4);
  int* cursor  = (int*)take((size_t)N_NODES * 4);
  int* csr_src = (int*)take((size_t)(N_EDGES + N_NODES) * 4);
  int* csr_eid = (int*)take((size_t)(N_EDGES + N_NODES) * 4);
  float* a_s  = (float*)take((size_t)N_NODES * NHEADS * 4);   // contiguous with a_d
  float* a_d  = (float*)take((size_t)N_NODES * NHEADS * 4);
  float* a_e  = (float*)take((size_t)N_EDGES * NHEADS * 4);
  ushort* Ahi = (ushort*)take((size_t)N_NODES * 256 * 2);
  ushort* Alo = (ushort*)take((size_t)N_NODES * 256 * 2);
  ushort* Bthi = (ushort*)take((size_t)512 * 256 * 2);
  ushort* Btlo = (ushort*)take((size_t)512 * 256 * 2);
  __half* h16 = (__half*)take((size_t)N_NODES * 512 * 2);
  float* ybuf = (float*)take((size_t)N_NODES * 256 * 4);

  const int* srcp = ei;
  const int* dstp = ei + N_EDGES;

  hipMemsetAsync(zero_region, 0, (16 + 8192 + 64) * 4, stream);
  ea_colsum_kernel<<<512, 256, 0, stream>>>(ea, ea_sum, N_EDGES);
  deg_init_kernel<<<(N_NODES + 255) / 256, 256, 0, stream>>>(deg, N_NODES);
  deg_count_kernel<<<2048, 256, 0, stream>>>(dstp, deg, N_EDGES);
  scan_kernel<<<1, 1024, 0, stream>>>(deg, offsets, cursor, N_NODES);
  scatter_kernel<<<2048, 256, 0, stream>>>(srcp, dstp, cursor, csr_src, csr_eid,
                                           N_EDGES, N_NODES);
  wvec_kernel<<<1, 256, 0, stream>>>(Wep[0], aep[0], Wep[1], aep[1], Wep[2], aep[2],
                                     ea_sum, wvec, ae_self);

  const float* cur_in = x;
  for (int l = 0; l < 3; ++l) {
    int K = (l == 0) ? 128 : 256;
    int kshift = (l == 0) ? 7 : 8;
    int C = (l == 2) ? 128 : 64;
    int HC = NHEADS * C;
    // zero a_s and a_d (contiguous allocations)
    hipMemsetAsync(a_s, 0, (size_t)N_NODES * NHEADS * 4 * 2, stream);
    int nA = N_NODES * K;
    split_kernel<<<2048, 256, 0, stream>>>(cur_in, Ahi, Alo, nA);
    int nB = HC * K;
    splitT_kernel<<<(nB + 255) / 256, 256, 0, stream>>>(W[l], Bthi, Btlo, kshift, HC, nB);
    gemm_mfma_kernel<<<dim3(HC / 64, (N_NODES + 63) / 64), 256, 0, stream>>>(
        Ahi, Alo, Bthi, Btlo, h16, asrc[l], adst[l], a_s, a_d, N_NODES, K, HC, C);
    ae_kernel<<<2048, 256, 0, stream>>>(ea, wvec + l * 64, a_e, N_EDGES);
    if (l < 2)
      agg_kernel<64, 0><<<N_NODES, 256, 0, stream>>>(h16, a_s, a_d, a_e,
                                                     ae_self + l * 4, offsets, csr_src,
                                                     csr_eid, bp[l], ybuf);
    else
      agg_kernel<128, 1><<<N_NODES, 256, 0, stream>>>(h16, a_s, a_d, a_e,
                                                      ae_self + l * 4, offsets, csr_src,
                                                      csr_eid, bp[l], ybuf);
    cur_in = ybuf;
  }
  pool_kernel<<<(N_NODES + 255) / 256, 128, 0, stream>>>(ybuf, batch, pool, cnt, N_NODES);
  finalize_kernel<<<(8192 + 255) / 256, 256, 0, stream>>>(pool, cnt, (float*)d_out);
}

// Round 3
// 1182.493 us; speedup vs baseline: 1.2465x; 1.2465x over previous
//
#include <hip/hip_runtime.h>
#include <hip/hip_bf16.h>
#include <hip/hip_fp16.h>
#include <math.h>

#define N_NODES 50000
#define N_EDGES 800000
#define NHEADS  4
#define NEG_SLOPE 0.2f

typedef __attribute__((ext_vector_type(8))) short short8v;  // 8 bf16
typedef __attribute__((ext_vector_type(4))) float f32x4;

__device__ inline ushort f2bf(float f) {  // RNE float->bf16 bits
  uint u = __float_as_uint(f);
  u += 0x7FFFu + ((u >> 16) & 1u);
  return (ushort)(u >> 16);
}
__device__ inline float bf2f(ushort h) { return __uint_as_float((uint)h << 16); }

__device__ __forceinline__ void gld_lds16(const ushort* g, ushort* l) {
  __builtin_amdgcn_global_load_lds(
      (const __attribute__((address_space(1))) void*)g,
      (__attribute__((address_space(3))) void*)l, 16, 0, 0);
}

// ---------------------------------------------------------------------------
// split fp32 -> (hi, lo) bf16 pair (layer-0 input only)
// ---------------------------------------------------------------------------
__global__ void split_kernel(const float* __restrict__ in, ushort* __restrict__ hi,
                             ushort* __restrict__ lo, int n) {
  int i = blockIdx.x * blockDim.x + threadIdx.x;
  int s = gridDim.x * blockDim.x;
  for (; i < n; i += s) {
    float v = in[i];
    ushort h = f2bf(v);
    hi[i] = h;
    lo[i] = f2bf(v - bf2f(h));
  }
}

// split + transpose: W[K][N] -> Bt_hi/lo [N][K]
__global__ void splitT_kernel(const float* __restrict__ W, ushort* __restrict__ hi,
                              ushort* __restrict__ lo, int kshift, int N, int n) {
  int i = blockIdx.x * blockDim.x + threadIdx.x;
  if (i >= n) return;
  int K = 1 << kshift;
  int nn = i >> kshift, k = i & (K - 1);
  float v = W[(size_t)k * N + nn];
  ushort h = f2bf(v);
  hi[i] = h;
  lo[i] = f2bf(v - bf2f(h));
}

// ---------------------------------------------------------------------------
// split-bf16 MFMA GEMM, 128x128 tile, BK=32, LDS-staged via global_load_lds.
// C = Ahi*Bhi + Ahi*Blo + Alo*Bhi (fp32 accum).  Bt is [N][K].
// 4 waves; wave w -> 64x64 quadrant (wm=w>>1, wn=w&1).
// LDS chunk swizzle: slot(row,kg) = row*4 + (kg ^ ((row>>1)&3)); the global
// SOURCE is pre-swizzled and the ds_read applies the same XOR (both-sides).
// Epilogue: h16 (fp16) + a_s/a_d = h . asrc/adst via 16-lane reduce + atomics.
// ---------------------------------------------------------------------------
__global__ __launch_bounds__(256) void gemm_mfma_kernel(
    const ushort* __restrict__ Ahi, const ushort* __restrict__ Alo,
    const ushort* __restrict__ Bthi, const ushort* __restrict__ Btlo,
    __half* __restrict__ h16, const float* __restrict__ asrc,
    const float* __restrict__ adst, float* __restrict__ a_s,
    float* __restrict__ a_d, int M, int K, int N, int Cph) {
  __shared__ ushort lds[4 * 4096];  // [mat][512 slots * 8 ushort] = 32 KB
  int tid = threadIdx.x;
  int lane = tid & 63, w = tid >> 6;
  int wm = w >> 1, wn = w & 1;
  int r16 = lane & 15, kgrp = lane >> 4;
  int bm = blockIdx.y * 128, bn = blockIdx.x * 128;

  // 8 staging source pointers (chunk c = i*256 + tid; mat = c>>9, slot = c&511)
  const ushort* gp[8];
#pragma unroll
  for (int i = 0; i < 8; ++i) {
    int c = i * 256 + tid;
    int mmat = c >> 9;
    int s = c & 511;
    int row = s >> 2;
    int kg = (s & 3) ^ ((row >> 1) & 3);  // pre-swizzled source chunk
    const ushort* base;
    int rowg;
    if (mmat == 0)      { base = Ahi;  rowg = min(bm + row, M - 1); }
    else if (mmat == 1) { base = Alo;  rowg = min(bm + row, M - 1); }
    else if (mmat == 2) { base = Bthi; rowg = bn + row; }
    else                { base = Btlo; rowg = bn + row; }
    gp[i] = base + (size_t)rowg * K + kg * 8;
  }

  f32x4 acc[4][4] = {};
  for (int k0 = 0; k0 < K; k0 += 32) {
#pragma unroll
    for (int i = 0; i < 8; ++i)
      gld_lds16(gp[i] + k0, lds + i * 2048 + tid * 8);
    __syncthreads();
    short8v ah[4], al[4], bh[4], bl[4];
#pragma unroll
    for (int m = 0; m < 4; ++m) {
      int row = wm * 64 + m * 16 + r16;
      int s = row * 4 + (kgrp ^ ((row >> 1) & 3));
      ah[m] = *(const short8v*)(lds + 0 * 4096 + s * 8);
      al[m] = *(const short8v*)(lds + 1 * 4096 + s * 8);
    }
#pragma unroll
    for (int j = 0; j < 4; ++j) {
      int row = wn * 64 + j * 16 + r16;
      int s = row * 4 + (kgrp ^ ((row >> 1) & 3));
      bh[j] = *(const short8v*)(lds + 2 * 4096 + s * 8);
      bl[j] = *(const short8v*)(lds + 3 * 4096 + s * 8);
    }
#pragma unroll
    for (int m = 0; m < 4; ++m)
#pragma unroll
      for (int j = 0; j < 4; ++j) {
        acc[m][j] = __builtin_amdgcn_mfma_f32_16x16x32_bf16(ah[m], bh[j], acc[m][j], 0, 0, 0);
        acc[m][j] = __builtin_amdgcn_mfma_f32_16x16x32_bf16(ah[m], bl[j], acc[m][j], 0, 0, 0);
        acc[m][j] = __builtin_amdgcn_mfma_f32_16x16x32_bf16(al[m], bh[j], acc[m][j], 0, 0, 0);
      }
    __syncthreads();
  }

  int colbase = bn + wn * 64;
  int hd = colbase / Cph;  // wave-uniform head
#pragma unroll
  for (int m = 0; m < 4; ++m) {
#pragma unroll
    for (int r = 0; r < 4; ++r) {
      int row = bm + wm * 64 + m * 16 + kgrp * 4 + r;
      bool ok = row < M;
      float ps = 0.f, pd = 0.f;
#pragma unroll
      for (int j = 0; j < 4; ++j) {
        float val = acc[m][j][r];
        int col = colbase + 16 * j + r16;
        if (ok) h16[(size_t)row * N + col] = __float2half(val);
        ps += val * asrc[col];
        pd += val * adst[col];
      }
#pragma unroll
      for (int o = 8; o >= 1; o >>= 1) {
        ps += __shfl_xor(ps, o);
        pd += __shfl_xor(pd, o);
      }
      if (r16 == 0 && ok) {
        atomicAdd(&a_s[row * NHEADS + hd], ps);
        atomicAdd(&a_d[row * NHEADS + hd], pd);
      }
    }
  }
}

// ---------------------------------------------------------------------------
// edge_attr column sums (for mean)
// ---------------------------------------------------------------------------
__global__ void ea_colsum_kernel(const float* __restrict__ ea,
                                 float* __restrict__ sums, int E) {
  int tid = threadIdx.x;
  int col = tid & 15;
  float s = 0.f;
  for (int r = blockIdx.x * 16 + (tid >> 4); r < E; r += gridDim.x * 16)
    s += ea[(size_t)r * 16 + col];
  __shared__ float red[256];
  red[tid] = s;
  __syncthreads();
  for (int off = 128; off >= 16; off >>= 1) {
    if (tid < off) red[tid] += red[tid + off];
    __syncthreads();
  }
  if (tid < 16) atomicAdd(&sums[tid], red[tid]);
}

// ---------------------------------------------------------------------------
// wvec[l][k][h] = sum_c We_l[k, h*C+c] * ae_l[h,c];  ae_self[l][h] from mean ea
// ---------------------------------------------------------------------------
__global__ void wvec_kernel(const float* __restrict__ We0, const float* __restrict__ ae0,
                            const float* __restrict__ We1, const float* __restrict__ ae1,
                            const float* __restrict__ We2, const float* __restrict__ ae2,
                            const float* __restrict__ ea_sum,
                            float* __restrict__ wvec, float* __restrict__ ae_self) {
  __shared__ float sw[192];
  int tid = threadIdx.x;
  if (tid < 192) {
    int l = tid >> 6, rem = tid & 63, k = rem >> 2, hd = rem & 3;
    int C = (l == 2) ? 128 : 64;
    const float* We = (l == 0) ? We0 : (l == 1) ? We1 : We2;
    const float* ae = (l == 0) ? ae0 : (l == 1) ? ae1 : ae2;
    float s = 0.f;
    for (int c = 0; c < C; ++c) s += We[(size_t)k * (4 * C) + hd * C + c] * ae[hd * C + c];
    sw[tid] = s;
    wvec[tid] = s;  // layout: l*64 + k*4 + hd
  }
  __syncthreads();
  if (tid < 12) {
    int l = tid >> 2, hd = tid & 3;
    const float invE = 1.0f / (float)N_EDGES;
    float s = 0.f;
    for (int k = 0; k < 16; ++k) s += ea_sum[k] * invE * sw[l * 64 + k * 4 + hd];
    ae_self[tid] = s;
  }
}

// ---------------------------------------------------------------------------
// a_e for ALL 3 layers in one pass over ea: a_e[l][e][h] = sum_k ea[e,k]*wv[l,k,h]
// ---------------------------------------------------------------------------
__global__ void ae_all_kernel(const float* __restrict__ ea, const float* __restrict__ wv,
                              float* __restrict__ a_e, int E) {
  int i = blockIdx.x * blockDim.x + threadIdx.x;
  int stride = gridDim.x * blockDim.x;
  for (int e = i; e < E; e += stride) {
    float row[16];
    const float4* rp = (const float4*)(ea + (size_t)e * 16);
#pragma unroll
    for (int q = 0; q < 4; ++q) {
      float4 v = rp[q];
      row[q * 4 + 0] = v.x; row[q * 4 + 1] = v.y;
      row[q * 4 + 2] = v.z; row[q * 4 + 3] = v.w;
    }
#pragma unroll
    for (int l = 0; l < 3; ++l) {
      float s0 = 0, s1 = 0, s2 = 0, s3 = 0;
#pragma unroll
      for (int k = 0; k < 16; ++k) {
        float v = row[k];
        s0 += v * wv[l * 64 + k * 4 + 0];
        s1 += v * wv[l * 64 + k * 4 + 1];
        s2 += v * wv[l * 64 + k * 4 + 2];
        s3 += v * wv[l * 64 + k * 4 + 3];
      }
      *(float4*)(a_e + ((size_t)l * E + e) * 4) = make_float4(s0, s1, s2, s3);
    }
  }
}

// ---------------------------------------------------------------------------
// CSR build
// ---------------------------------------------------------------------------
__global__ void deg_init_kernel(int* deg, int n) {
  int i = blockIdx.x * blockDim.x + threadIdx.x;
  if (i < n) deg[i] = 1;  // self-loop
}
__global__ void deg_count_kernel(const int* __restrict__ dst, int* deg, int E) {
  int i = blockIdx.x * blockDim.x + threadIdx.x;
  int s = gridDim.x * blockDim.x;
  for (; i < E; i += s) atomicAdd(&deg[dst[i]], 1);
}
__global__ void scan_kernel(const int* __restrict__ deg, int* __restrict__ offsets,
                            int* __restrict__ cursor, int n) {
  __shared__ int sums[1024];
  int tid = threadIdx.x;
  int chunk = (n + 1023) >> 10;
  int lo = tid * chunk; if (lo > n) lo = n;
  int hi = lo + chunk;  if (hi > n) hi = n;
  int s = 0;
  for (int i = lo; i < hi; ++i) s += deg[i];
  sums[tid] = s;
  __syncthreads();
  for (int d = 1; d < 1024; d <<= 1) {
    int v = (tid >= d) ? sums[tid - d] : 0;
    __syncthreads();
    sums[tid] += v;
    __syncthreads();
  }
  int run = (tid > 0) ? sums[tid - 1] : 0;
  for (int i = lo; i < hi; ++i) {
    offsets[i] = run;
    cursor[i] = run;
    run += deg[i];
  }
  if (tid == 0) offsets[n] = sums[1023];
}
__global__ void scatter_kernel(const int* __restrict__ src, const int* __restrict__ dst,
                               int* cursor, int* __restrict__ csr_src,
                               int* __restrict__ csr_eid, int E, int n) {
  int i = blockIdx.x * blockDim.x + threadIdx.x;
  int s = gridDim.x * blockDim.x;
  int tot = E + n;
  for (; i < tot; i += s) {
    int ss, dd, eid;
    if (i < E) { ss = src[i]; dd = dst[i]; eid = i; }
    else       { ss = i - E; dd = ss;     eid = E; }   // self-loop sentinel
    int pos = atomicAdd(&cursor[dd], 1);
    csr_src[pos] = ss;
    csr_eid[pos] = eid;
  }
}

// ---------------------------------------------------------------------------
// aggregation: per-dst softmax + weighted sum of h[src] (fp16 gather).
// MODE 0: concat + bias + ELU -> write bf16 hi/lo split (next layer's A)
// MODE 1: head-mean + bias -> write fp32 (pool input)
// ---------------------------------------------------------------------------
template <int C, int MODE>
__global__ __launch_bounds__(256) void agg_kernel(
    const __half* __restrict__ h, const float* __restrict__ a_s,
    const float* __restrict__ a_d, const float* __restrict__ a_e,
    const float* __restrict__ ae_self, const int* __restrict__ offsets,
    const int* __restrict__ csr_src, const int* __restrict__ csr_eid,
    const float* __restrict__ bias, ushort* __restrict__ yhi,
    ushort* __restrict__ ylo, float* __restrict__ yf) {
  constexpr int HC = NHEADS * C;
  int node = blockIdx.x;
  int hd = threadIdx.x >> 6, l = threadIdx.x & 63;
  int beg = offsets[node], end = offsets[node + 1];
  float a_dn = a_d[node * NHEADS + hd];
  float aes = ae_self[hd];
  float acc0 = 0.f, acc1 = 0.f, denom = 0.f;

  if (end - beg <= 64) {
    int j = beg + l;
    bool valid = j < end;
    int s = 0;
    float al = -1e30f;
    if (valid) {
      s = csr_src[j];
      int eid = csr_eid[j];
      float aev = (eid < N_EDGES) ? a_e[(size_t)eid * NHEADS + hd] : aes;
      float v = a_s[s * NHEADS + hd] + a_dn + aev;
      al = (v > 0.f) ? v : NEG_SLOPE * v;
    }
    float m = al;
#pragma unroll
    for (int o = 32; o >= 1; o >>= 1) m = fmaxf(m, __shfl_xor(m, o));
    float ex = valid ? __expf(al - m) : 0.f;
    denom = ex;
#pragma unroll
    for (int o = 32; o >= 1; o >>= 1) denom += __shfl_xor(denom, o);
    int cnt = end - beg;
    for (int t = 0; t < cnt; ++t) {
      float w = __shfl(ex, t);
      int ss = __shfl(s, t);
      const __half* hp = h + (size_t)ss * HC + hd * C;
      acc0 += w * __half2float(hp[l]);
      if (C == 128) acc1 += w * __half2float(hp[64 + l]);
    }
  } else {
    float m = -1e30f;
    for (int j0 = beg; j0 < end; j0 += 64) {
      int j = j0 + l;
      float al = -1e30f;
      if (j < end) {
        int s = csr_src[j];
        int eid = csr_eid[j];
        float aev = (eid < N_EDGES) ? a_e[(size_t)eid * NHEADS + hd] : aes;
        float v = a_s[s * NHEADS + hd] + a_dn + aev;
        al = (v > 0.f) ? v : NEG_SLOPE * v;
      }
      m = fmaxf(m, al);
    }
#pragma unroll
    for (int o = 32; o >= 1; o >>= 1) m = fmaxf(m, __shfl_xor(m, o));
    for (int j0 = beg; j0 < end; j0 += 64) {
      int j = j0 + l;
      int s = 0;
      float ex = 0.f;
      if (j < end) {
        int ss0 = csr_src[j];
        int eid = csr_eid[j];
        float aev = (eid < N_EDGES) ? a_e[(size_t)eid * NHEADS + hd] : aes;
        float v = a_s[ss0 * NHEADS + hd] + a_dn + aev;
        float al = (v > 0.f) ? v : NEG_SLOPE * v;
        ex = __expf(al - m);
        s = ss0;
      }
      denom += ex;
      int cnt = min(64, end - j0);
      for (int t = 0; t < cnt; ++t) {
        float w = __shfl(ex, t);
        int ss = __shfl(s, t);
        const __half* hp = h + (size_t)ss * HC + hd * C;
        acc0 += w * __half2float(hp[l]);
        if (C == 128) acc1 += w * __half2float(hp[64 + l]);
      }
    }
#pragma unroll
    for (int o = 32; o >= 1; o >>= 1) denom += __shfl_xor(denom, o);
  }

  float inv = 1.0f / (denom + 1e-16f);
  float v0 = acc0 * inv;
  if (MODE == 0) {
    float o = v0 + bias[hd * C + l];
    o = (o > 0.f) ? o : (__expf(o) - 1.f);
    size_t idx = (size_t)node * HC + hd * C + l;
    ushort hb = f2bf(o);
    yhi[idx] = hb;
    ylo[idx] = f2bf(o - bf2f(hb));
  } else {
    float v1 = acc1 * inv;
    __shared__ float red[NHEADS][128];
    red[hd][l] = v0;
    red[hd][64 + l] = v1;
    __syncthreads();
    if (hd == 0) {
#pragma unroll
      for (int q = 0; q < 2; ++q) {
        int c = l + q * 64;
        float sum = (red[0][c] + red[1][c] + red[2][c] + red[3][c]) * 0.25f + bias[c];
        yf[(size_t)node * 128 + c] = sum;
      }
    }
  }
}

// ---------------------------------------------------------------------------
// global mean pool
// ---------------------------------------------------------------------------
__global__ void pool_kernel(const float* __restrict__ y, const int* __restrict__ batch,
                            float* __restrict__ pool, float* __restrict__ cnt, int n) {
  int n0 = blockIdx.x * 256;
  if (n0 >= n) return;
  int n1 = min(n0 + 256, n);
  int c = threadIdx.x;  // 128 threads
  float accum = 0.f;
  int cur = batch[n0];
  int cn = 0;
  for (int nd = n0; nd < n1; ++nd) {
    int g = batch[nd];
    if (g != cur) {
      atomicAdd(&pool[cur * 128 + c], accum);
      if (c == 0) atomicAdd(&cnt[cur], (float)cn);
      accum = 0.f; cn = 0; cur = g;
    }
    accum += y[(size_t)nd * 128 + c];
    cn++;
  }
  atomicAdd(&pool[cur * 128 + c], accum);
  if (c == 0) atomicAdd(&cnt[cur], (float)cn);
}
__global__ void finalize_kernel(const float* __restrict__ pool,
                                const float* __restrict__ cnt, float* __restrict__ out) {
  int i = blockIdx.x * blockDim.x + threadIdx.x;
  if (i < 64 * 128) out[i] = pool[i] / fmaxf(cnt[i >> 7], 1.f);
}

// ---------------------------------------------------------------------------
extern "C" void kernel_launch(void* const* d_in, const int* in_sizes, int n_in,
                              void* d_out, int out_size, void* d_ws, size_t ws_size,
                              hipStream_t stream) {
  const float* x = (const float*)d_in[0];
  const int* ei = (const int*)d_in[1];
  const float* ea = (const float*)d_in[2];
  const int* batch = (const int*)d_in[3];
  const float* W[3]    = {(const float*)d_in[4],  (const float*)d_in[10], (const float*)d_in[16]};
  const float* asrc[3] = {(const float*)d_in[5],  (const float*)d_in[11], (const float*)d_in[17]};
  const float* adst[3] = {(const float*)d_in[6],  (const float*)d_in[12], (const float*)d_in[18]};
  const float* Wep[3]  = {(const float*)d_in[7],  (const float*)d_in[13], (const float*)d_in[19]};
  const float* aep[3]  = {(const float*)d_in[8],  (const float*)d_in[14], (const float*)d_in[20]};
  const float* bp[3]   = {(const float*)d_in[9],  (const float*)d_in[15], (const float*)d_in[21]};

  char* ws = (char*)d_ws;
  size_t off = 0;
  auto take = [&](size_t bytes) -> void* {
    void* p = ws + off;
    off = (off + bytes + 255) & ~(size_t)255;
    return p;
  };
  float* zero_region = (float*)take((16 + 8192 + 64) * 4);
  float* ea_sum = zero_region;
  float* pool   = zero_region + 16;
  float* cnt    = zero_region + 16 + 8192;
  float* wvec    = (float*)take(192 * 4);
  float* ae_self = (float*)take(12 * 4);
  int* deg     = (int*)take((size_t)N_NODES * 4);
  int* offsets = (int*)take(((size_t)N_NODES + 1) * 4);
  int* cursor  = (int*)take((size_t)N_NODES * 4);
  int* csr_src = (int*)take((size_t)(N_EDGES + N_NODES) * 4);
  int* csr_eid = (int*)take((size_t)(N_EDGES + N_NODES) * 4);
  float* a_s  = (float*)take((size_t)N_NODES * NHEADS * 4);   // contiguous with a_d
  float* a_d  = (float*)take((size_t)N_NODES * NHEADS * 4);
  float* a_e  = (float*)take((size_t)3 * N_EDGES * NHEADS * 4);  // all 3 layers
  ushort* Ahi = (ushort*)take((size_t)N_NODES * 256 * 2);
  ushort* Alo = (ushort*)take((size_t)N_NODES * 256 * 2);
  ushort* Bthi = (ushort*)take((size_t)512 * 256 * 2);
  ushort* Btlo = (ushort*)take((size_t)512 * 256 * 2);
  __half* h16 = (__half*)take((size_t)N_NODES * 512 * 2);
  float* ybuf = (float*)take((size_t)N_NODES * 128 * 4);

  const int* srcp = ei;
  const int* dstp = ei + N_EDGES;

  hipMemsetAsync(zero_region, 0, (16 + 8192 + 64) * 4, stream);
  ea_colsum_kernel<<<512, 256, 0, stream>>>(ea, ea_sum, N_EDGES);
  deg_init_kernel<<<(N_NODES + 255) / 256, 256, 0, stream>>>(deg, N_NODES);
  deg_count_kernel<<<2048, 256, 0, stream>>>(dstp, deg, N_EDGES);
  scan_kernel<<<1, 1024, 0, stream>>>(deg, offsets, cursor, N_NODES);
  scatter_kernel<<<2048, 256, 0, stream>>>(srcp, dstp, cursor, csr_src, csr_eid,
                                           N_EDGES, N_NODES);
  wvec_kernel<<<1, 256, 0, stream>>>(Wep[0], aep[0], Wep[1], aep[1], Wep[2], aep[2],
                                     ea_sum, wvec, ae_self);
  ae_all_kernel<<<2048, 256, 0, stream>>>(ea, wvec, a_e, N_EDGES);
  split_kernel<<<2048, 256, 0, stream>>>(x, Ahi, Alo, N_NODES * 128);

  for (int l = 0; l < 3; ++l) {
    int K = (l == 0) ? 128 : 256;
    int kshift = (l == 0) ? 7 : 8;
    int C = (l == 2) ? 128 : 64;
    int HC = NHEADS * C;
    hipMemsetAsync(a_s, 0, (size_t)N_NODES * NHEADS * 4 * 2, stream);
    int nB = HC * K;
    splitT_kernel<<<(nB + 255) / 256, 256, 0, stream>>>(W[l], Bthi, Btlo, kshift, HC, nB);
    gemm_mfma_kernel<<<dim3(HC / 128, (N_NODES + 127) / 128), 256, 0, stream>>>(
        Ahi, Alo, Bthi, Btlo, h16, asrc[l], adst[l], a_s, a_d, N_NODES, K, HC, C);
    if (l < 2)
      agg_kernel<64, 0><<<N_NODES, 256, 0, stream>>>(
          h16, a_s, a_d, a_e + (size_t)l * N_EDGES * NHEADS, ae_self + l * 4, offsets,
          csr_src, csr_eid, bp[l], Ahi, Alo, nullptr);
    else
      agg_kernel<128, 1><<<N_NODES, 256, 0, stream>>>(
          h16, a_s, a_d, a_e + (size_t)l * N_EDGES * NHEADS, ae_self + l * 4, offsets,
          csr_src, csr_eid, bp[l], nullptr, nullptr, ybuf);
  }
  pool_kernel<<<(N_NODES + 255) / 256, 128, 0, stream>>>(ybuf, batch, pool, cnt, N_NODES);
  finalize_kernel<<<(8192 + 255) / 256, 256, 0, stream>>>(pool, cnt, (float*)d_out);
}

// Round 4
// 899.768 us; speedup vs baseline: 1.6382x; 1.3142x over previous
//
#include <hip/hip_runtime.h>
#include <hip/hip_bf16.h>
#include <hip/hip_fp16.h>
#include <math.h>

#define N_NODES 50000
#define N_EDGES 800000
#define NHEADS  4
#define NEG_SLOPE 0.2f

typedef __attribute__((ext_vector_type(8))) short short8v;  // 8 bf16
typedef __attribute__((ext_vector_type(4))) float f32x4;

__device__ inline ushort f2bf(float f) {  // RNE float->bf16 bits
  uint u = __float_as_uint(f);
  u += 0x7FFFu + ((u >> 16) & 1u);
  return (ushort)(u >> 16);
}
__device__ inline float bf2f(ushort h) { return __uint_as_float((uint)h << 16); }

__device__ __forceinline__ void gld_lds16(const ushort* g, ushort* l) {
  __builtin_amdgcn_global_load_lds(
      (const __attribute__((address_space(1))) void*)g,
      (__attribute__((address_space(3))) void*)l, 16, 0, 0);
}

// ---------------------------------------------------------------------------
// split fp32 -> (hi, lo) bf16 pair (layer-0 input only)
// ---------------------------------------------------------------------------
__global__ void split_kernel(const float* __restrict__ in, ushort* __restrict__ hi,
                             ushort* __restrict__ lo, int n) {
  int i = blockIdx.x * blockDim.x + threadIdx.x;
  int s = gridDim.x * blockDim.x;
  for (; i < n; i += s) {
    float v = in[i];
    ushort h = f2bf(v);
    hi[i] = h;
    lo[i] = f2bf(v - bf2f(h));
  }
}

// split + transpose: W[K][N] -> Bt_hi/lo [N][K]
__global__ void splitT_kernel(const float* __restrict__ W, ushort* __restrict__ hi,
                              ushort* __restrict__ lo, int kshift, int N, int n) {
  int i = blockIdx.x * blockDim.x + threadIdx.x;
  if (i >= n) return;
  int K = 1 << kshift;
  int nn = i >> kshift, k = i & (K - 1);
  float v = W[(size_t)k * N + nn];
  ushort h = f2bf(v);
  hi[i] = h;
  lo[i] = f2bf(v - bf2f(h));
}

// ---------------------------------------------------------------------------
// split-bf16 MFMA GEMM, 128x128 tile, BK=32, LDS-staged via global_load_lds.
// ---------------------------------------------------------------------------
__global__ __launch_bounds__(256) void gemm_mfma_kernel(
    const ushort* __restrict__ Ahi, const ushort* __restrict__ Alo,
    const ushort* __restrict__ Bthi, const ushort* __restrict__ Btlo,
    __half* __restrict__ h16, const float* __restrict__ asrc,
    const float* __restrict__ adst, float* __restrict__ a_s,
    float* __restrict__ a_d, int M, int K, int N, int Cph) {
  __shared__ ushort lds[4 * 4096];  // [mat][512 slots * 8 ushort] = 32 KB
  int tid = threadIdx.x;
  int lane = tid & 63, w = tid >> 6;
  int wm = w >> 1, wn = w & 1;
  int r16 = lane & 15, kgrp = lane >> 4;
  int bm = blockIdx.y * 128, bn = blockIdx.x * 128;

  const ushort* gp[8];
#pragma unroll
  for (int i = 0; i < 8; ++i) {
    int c = i * 256 + tid;
    int mmat = c >> 9;
    int s = c & 511;
    int row = s >> 2;
    int kg = (s & 3) ^ ((row >> 1) & 3);  // pre-swizzled source chunk
    const ushort* base;
    int rowg;
    if (mmat == 0)      { base = Ahi;  rowg = min(bm + row, M - 1); }
    else if (mmat == 1) { base = Alo;  rowg = min(bm + row, M - 1); }
    else if (mmat == 2) { base = Bthi; rowg = bn + row; }
    else                { base = Btlo; rowg = bn + row; }
    gp[i] = base + (size_t)rowg * K + kg * 8;
  }

  f32x4 acc[4][4] = {};
  for (int k0 = 0; k0 < K; k0 += 32) {
#pragma unroll
    for (int i = 0; i < 8; ++i)
      gld_lds16(gp[i] + k0, lds + i * 2048 + tid * 8);
    __syncthreads();
    short8v ah[4], al[4], bh[4], bl[4];
#pragma unroll
    for (int m = 0; m < 4; ++m) {
      int row = wm * 64 + m * 16 + r16;
      int s = row * 4 + (kgrp ^ ((row >> 1) & 3));
      ah[m] = *(const short8v*)(lds + 0 * 4096 + s * 8);
      al[m] = *(const short8v*)(lds + 1 * 4096 + s * 8);
    }
#pragma unroll
    for (int j = 0; j < 4; ++j) {
      int row = wn * 64 + j * 16 + r16;
      int s = row * 4 + (kgrp ^ ((row >> 1) & 3));
      bh[j] = *(const short8v*)(lds + 2 * 4096 + s * 8);
      bl[j] = *(const short8v*)(lds + 3 * 4096 + s * 8);
    }
#pragma unroll
    for (int m = 0; m < 4; ++m)
#pragma unroll
      for (int j = 0; j < 4; ++j) {
        acc[m][j] = __builtin_amdgcn_mfma_f32_16x16x32_bf16(ah[m], bh[j], acc[m][j], 0, 0, 0);
        acc[m][j] = __builtin_amdgcn_mfma_f32_16x16x32_bf16(ah[m], bl[j], acc[m][j], 0, 0, 0);
        acc[m][j] = __builtin_amdgcn_mfma_f32_16x16x32_bf16(al[m], bh[j], acc[m][j], 0, 0, 0);
      }
    __syncthreads();
  }

  int colbase = bn + wn * 64;
  int hd = colbase / Cph;  // wave-uniform head
#pragma unroll
  for (int m = 0; m < 4; ++m) {
#pragma unroll
    for (int r = 0; r < 4; ++r) {
      int row = bm + wm * 64 + m * 16 + kgrp * 4 + r;
      bool ok = row < M;
      float ps = 0.f, pd = 0.f;
#pragma unroll
      for (int j = 0; j < 4; ++j) {
        float val = acc[m][j][r];
        int col = colbase + 16 * j + r16;
        if (ok) h16[(size_t)row * N + col] = __float2half(val);
        ps += val * asrc[col];
        pd += val * adst[col];
      }
#pragma unroll
      for (int o = 8; o >= 1; o >>= 1) {
        ps += __shfl_xor(ps, o);
        pd += __shfl_xor(pd, o);
      }
      if (r16 == 0 && ok) {
        atomicAdd(&a_s[row * NHEADS + hd], ps);
        atomicAdd(&a_d[row * NHEADS + hd], pd);
      }
    }
  }
}

// ---------------------------------------------------------------------------
// edge_attr column sums (for mean)
// ---------------------------------------------------------------------------
__global__ void ea_colsum_kernel(const float* __restrict__ ea,
                                 float* __restrict__ sums, int E) {
  int tid = threadIdx.x;
  int col = tid & 15;
  float s = 0.f;
  for (int r = blockIdx.x * 16 + (tid >> 4); r < E; r += gridDim.x * 16)
    s += ea[(size_t)r * 16 + col];
  __shared__ float red[256];
  red[tid] = s;
  __syncthreads();
  for (int off = 128; off >= 16; off >>= 1) {
    if (tid < off) red[tid] += red[tid + off];
    __syncthreads();
  }
  if (tid < 16) atomicAdd(&sums[tid], red[tid]);
}

// ---------------------------------------------------------------------------
// wvec[l][k][h] = sum_c We_l[k, h*C+c] * ae_l[h,c];  ae_self[l][h] from mean ea
// ---------------------------------------------------------------------------
__global__ void wvec_kernel(const float* __restrict__ We0, const float* __restrict__ ae0,
                            const float* __restrict__ We1, const float* __restrict__ ae1,
                            const float* __restrict__ We2, const float* __restrict__ ae2,
                            const float* __restrict__ ea_sum,
                            float* __restrict__ wvec, float* __restrict__ ae_self) {
  __shared__ float sw[192];
  int tid = threadIdx.x;
  if (tid < 192) {
    int l = tid >> 6, rem = tid & 63, k = rem >> 2, hd = rem & 3;
    int C = (l == 2) ? 128 : 64;
    const float* We = (l == 0) ? We0 : (l == 1) ? We1 : We2;
    const float* ae = (l == 0) ? ae0 : (l == 1) ? ae1 : ae2;
    float s = 0.f;
    for (int c = 0; c < C; ++c) s += We[(size_t)k * (4 * C) + hd * C + c] * ae[hd * C + c];
    sw[tid] = s;
    wvec[tid] = s;  // layout: l*64 + k*4 + hd
  }
  __syncthreads();
  if (tid < 12) {
    int l = tid >> 2, hd = tid & 3;
    const float invE = 1.0f / (float)N_EDGES;
    float s = 0.f;
    for (int k = 0; k < 16; ++k) s += ea_sum[k] * invE * sw[l * 64 + k * 4 + hd];
    ae_self[tid] = s;
  }
}

// ---------------------------------------------------------------------------
// a_e for ALL 3 layers in one pass over ea
// ---------------------------------------------------------------------------
__global__ void ae_all_kernel(const float* __restrict__ ea, const float* __restrict__ wv,
                              float* __restrict__ a_e, int E) {
  int i = blockIdx.x * blockDim.x + threadIdx.x;
  int stride = gridDim.x * blockDim.x;
  for (int e = i; e < E; e += stride) {
    float row[16];
    const float4* rp = (const float4*)(ea + (size_t)e * 16);
#pragma unroll
    for (int q = 0; q < 4; ++q) {
      float4 v = rp[q];
      row[q * 4 + 0] = v.x; row[q * 4 + 1] = v.y;
      row[q * 4 + 2] = v.z; row[q * 4 + 3] = v.w;
    }
#pragma unroll
    for (int l = 0; l < 3; ++l) {
      float s0 = 0, s1 = 0, s2 = 0, s3 = 0;
#pragma unroll
      for (int k = 0; k < 16; ++k) {
        float v = row[k];
        s0 += v * wv[l * 64 + k * 4 + 0];
        s1 += v * wv[l * 64 + k * 4 + 1];
        s2 += v * wv[l * 64 + k * 4 + 2];
        s3 += v * wv[l * 64 + k * 4 + 3];
      }
      *(float4*)(a_e + ((size_t)l * E + e) * 4) = make_float4(s0, s1, s2, s3);
    }
  }
}

// ---------------------------------------------------------------------------
// CSR build
// ---------------------------------------------------------------------------
__global__ void deg_init_kernel(int* deg, int n) {
  int i = blockIdx.x * blockDim.x + threadIdx.x;
  if (i < n) deg[i] = 1;  // self-loop
}
__global__ void deg_count_kernel(const int* __restrict__ dst, int* deg, int E) {
  int i = blockIdx.x * blockDim.x + threadIdx.x;
  int s = gridDim.x * blockDim.x;
  for (; i < E; i += s) atomicAdd(&deg[dst[i]], 1);
}
__global__ void scan_kernel(const int* __restrict__ deg, int* __restrict__ offsets,
                            int* __restrict__ cursor, int n) {
  __shared__ int sums[1024];
  int tid = threadIdx.x;
  int chunk = (n + 1023) >> 10;
  int lo = tid * chunk; if (lo > n) lo = n;
  int hi = lo + chunk;  if (hi > n) hi = n;
  int s = 0;
  for (int i = lo; i < hi; ++i) s += deg[i];
  sums[tid] = s;
  __syncthreads();
  for (int d = 1; d < 1024; d <<= 1) {
    int v = (tid >= d) ? sums[tid - d] : 0;
    __syncthreads();
    sums[tid] += v;
    __syncthreads();
  }
  int run = (tid > 0) ? sums[tid - 1] : 0;
  for (int i = lo; i < hi; ++i) {
    offsets[i] = run;
    cursor[i] = run;
    run += deg[i];
  }
  if (tid == 0) offsets[n] = sums[1023];
}
__global__ void scatter_kernel(const int* __restrict__ src, const int* __restrict__ dst,
                               int* cursor, int* __restrict__ csr_src,
                               int* __restrict__ csr_eid, int E, int n) {
  int i = blockIdx.x * blockDim.x + threadIdx.x;
  int s = gridDim.x * blockDim.x;
  int tot = E + n;
  for (; i < tot; i += s) {
    int ss, dd, eid;
    if (i < E) { ss = src[i]; dd = dst[i]; eid = i; }
    else       { ss = i - E; dd = ss;     eid = E; }   // self-loop sentinel
    int pos = atomicAdd(&cursor[dd], 1);
    csr_src[pos] = ss;
    csr_eid[pos] = eid;
  }
}

// ---------------------------------------------------------------------------
// aggregation, restructured for MLP (memory-level parallelism):
// phase 1 (wave=head, lane=edge): softmax ex -> LDS exbuf/sbuf + denom.
// phase 2 (all 256 threads = HC/2 half2 slots x NGRP edge groups): gather
// h rows coalesced, 4 edges in flight per group (unroll-4), ex from LDS.
// MODE 0: concat + bias + ELU -> bf16 hi/lo split.  MODE 1: head-mean -> fp32.
// ---------------------------------------------------------------------------
template <int C, int MODE>
__global__ __launch_bounds__(256) void agg_kernel(
    const __half* __restrict__ h, const float* __restrict__ a_s,
    const float* __restrict__ a_d, const float* __restrict__ a_e,
    const float* __restrict__ ae_self, const int* __restrict__ offsets,
    const int* __restrict__ csr_src, const int* __restrict__ csr_eid,
    const float* __restrict__ bias, ushort* __restrict__ yhi,
    ushort* __restrict__ ylo, float* __restrict__ yf) {
  constexpr int HC = NHEADS * C;     // 256 or 512
  constexpr int NSLOT = HC / 2;      // half2 slots per row: 128 or 256
  constexpr int NGRP = 512 / HC;     // edge groups: 2 or 1
  constexpr int LOG_C = (C == 64) ? 6 : 7;

  __shared__ float exbuf[NHEADS][64];
  __shared__ int sbuf[64];
  __shared__ float dshare[NHEADS];
  __shared__ float2 cbuf[NSLOT];

  int node = blockIdx.x;
  int tid = threadIdx.x;
  int hd = tid >> 6, l = tid & 63;
  int beg = offsets[node], end = offsets[node + 1];
  int deg = end - beg;

  float a_dn = a_d[node * NHEADS + hd];
  float aes = ae_self[hd];

  // phase-2 mapping
  int i = tid & (NSLOT - 1);
  int g = (NGRP == 2) ? (tid >> 7) : 0;
  int hh = (2 * i) >> LOG_C;  // head owning this half2 slot
  float2 acc = make_float2(0.f, 0.f);
  const __half2* hp2 = (const __half2*)h;

  auto alpha_of = [&](int j, int& s_out) -> float {
    int s = csr_src[j];
    int eid = csr_eid[j];
    float aev = (eid < N_EDGES) ? a_e[(size_t)eid * NHEADS + hd] : aes;
    float v = a_s[s * NHEADS + hd] + a_dn + aev;
    s_out = s;
    return (v > 0.f) ? v : NEG_SLOPE * v;
  };

  auto accum_chunk = [&](int cnt) {
    int t = g;
    for (; t + 3 * NGRP < cnt; t += 4 * NGRP) {
      int s0 = sbuf[t], s1 = sbuf[t + NGRP];
      int s2 = sbuf[t + 2 * NGRP], s3 = sbuf[t + 3 * NGRP];
      __half2 r0 = hp2[(size_t)s0 * NSLOT + i];
      __half2 r1 = hp2[(size_t)s1 * NSLOT + i];
      __half2 r2 = hp2[(size_t)s2 * NSLOT + i];
      __half2 r3 = hp2[(size_t)s3 * NSLOT + i];
      float e0 = exbuf[hh][t], e1 = exbuf[hh][t + NGRP];
      float e2 = exbuf[hh][t + 2 * NGRP], e3 = exbuf[hh][t + 3 * NGRP];
      float2 f0 = __half22float2(r0), f1 = __half22float2(r1);
      float2 f2 = __half22float2(r2), f3 = __half22float2(r3);
      acc.x += e0 * f0.x + e1 * f1.x + e2 * f2.x + e3 * f3.x;
      acc.y += e0 * f0.y + e1 * f1.y + e2 * f2.y + e3 * f3.y;
    }
    for (; t < cnt; t += NGRP) {
      int s0 = sbuf[t];
      float2 f0 = __half22float2(hp2[(size_t)s0 * NSLOT + i]);
      float e0 = exbuf[hh][t];
      acc.x += e0 * f0.x;
      acc.y += e0 * f0.y;
    }
  };

  if (deg <= 64) {
    int j = beg + l;
    bool valid = j < end;
    int s = 0;
    float al = -1e30f;
    if (valid) al = alpha_of(j, s);
    float m = al;
#pragma unroll
    for (int o = 32; o >= 1; o >>= 1) m = fmaxf(m, __shfl_xor(m, o));
    float ex = valid ? __expf(al - m) : 0.f;
    float dsum = ex;
#pragma unroll
    for (int o = 32; o >= 1; o >>= 1) dsum += __shfl_xor(dsum, o);
    exbuf[hd][l] = ex;
    if (hd == 0) sbuf[l] = s;
    if (l == 0) dshare[hd] = dsum;
    __syncthreads();
    accum_chunk(deg);
  } else {
    float m = -1e30f;
    for (int j0 = beg; j0 < end; j0 += 64) {
      int j = j0 + l;
      if (j < end) {
        int s;
        m = fmaxf(m, alpha_of(j, s));
      }
    }
#pragma unroll
    for (int o = 32; o >= 1; o >>= 1) m = fmaxf(m, __shfl_xor(m, o));
    float dsum = 0.f;
    for (int j0 = beg; j0 < end; j0 += 64) {
      int j = j0 + l;
      int cnt = min(64, end - j0);
      float ex = 0.f;
      int s = 0;
      if (j < end) {
        float al = alpha_of(j, s);
        ex = __expf(al - m);
      }
      dsum += ex;
      __syncthreads();  // protect exbuf/sbuf from previous chunk's readers
      exbuf[hd][l] = ex;
      if (hd == 0) sbuf[l] = s;
      __syncthreads();
      accum_chunk(cnt);
    }
#pragma unroll
    for (int o = 32; o >= 1; o >>= 1) dsum += __shfl_xor(dsum, o);
    if (l == 0) dshare[hd] = dsum;
    __syncthreads();
  }

  if (NGRP == 2) {
    if (g == 1) cbuf[i] = acc;
    __syncthreads();
    if (tid < NSLOT) {
      float2 o = cbuf[i];
      acc.x += o.x;
      acc.y += o.y;
    }
  }

  if (MODE == 0) {
    if (tid < NSLOT) {
      float inv = 1.f / (dshare[hh] + 1e-16f);
      int c0 = 2 * i;
      float o0 = acc.x * inv + bias[c0];
      float o1 = acc.y * inv + bias[c0 + 1];
      o0 = (o0 > 0.f) ? o0 : (__expf(o0) - 1.f);
      o1 = (o1 > 0.f) ? o1 : (__expf(o1) - 1.f);
      size_t idx = (size_t)node * HC + c0;
      ushort b0 = f2bf(o0), b1 = f2bf(o1);
      yhi[idx] = b0;
      yhi[idx + 1] = b1;
      ylo[idx] = f2bf(o0 - bf2f(b0));
      ylo[idx + 1] = f2bf(o1 - bf2f(b1));
    }
  } else {
    float inv = 1.f / (dshare[hh] + 1e-16f);
    cbuf[i] = make_float2(acc.x * inv, acc.y * inv);
    __syncthreads();
    if (tid < 64) {
      float2 s0 = cbuf[tid], s1 = cbuf[tid + 64];
      float2 s2 = cbuf[tid + 128], s3 = cbuf[tid + 192];
      int c0 = 2 * tid;
      float o0 = (s0.x + s1.x + s2.x + s3.x) * 0.25f + bias[c0];
      float o1 = (s0.y + s1.y + s2.y + s3.y) * 0.25f + bias[c0 + 1];
      yf[(size_t)node * 128 + c0] = o0;
      yf[(size_t)node * 128 + c0 + 1] = o1;
    }
  }
}

// ---------------------------------------------------------------------------
// global mean pool
// ---------------------------------------------------------------------------
__global__ void pool_kernel(const float* __restrict__ y, const int* __restrict__ batch,
                            float* __restrict__ pool, float* __restrict__ cnt, int n) {
  int n0 = blockIdx.x * 256;
  if (n0 >= n) return;
  int n1 = min(n0 + 256, n);
  int c = threadIdx.x;  // 128 threads
  float accum = 0.f;
  int cur = batch[n0];
  int cn = 0;
  for (int nd = n0; nd < n1; ++nd) {
    int g = batch[nd];
    if (g != cur) {
      atomicAdd(&pool[cur * 128 + c], accum);
      if (c == 0) atomicAdd(&cnt[cur], (float)cn);
      accum = 0.f; cn = 0; cur = g;
    }
    accum += y[(size_t)nd * 128 + c];
    cn++;
  }
  atomicAdd(&pool[cur * 128 + c], accum);
  if (c == 0) atomicAdd(&cnt[cur], (float)cn);
}
__global__ void finalize_kernel(const float* __restrict__ pool,
                                const float* __restrict__ cnt, float* __restrict__ out) {
  int i = blockIdx.x * blockDim.x + threadIdx.x;
  if (i < 64 * 128) out[i] = pool[i] / fmaxf(cnt[i >> 7], 1.f);
}

// ---------------------------------------------------------------------------
extern "C" void kernel_launch(void* const* d_in, const int* in_sizes, int n_in,
                              void* d_out, int out_size, void* d_ws, size_t ws_size,
                              hipStream_t stream) {
  const float* x = (const float*)d_in[0];
  const int* ei = (const int*)d_in[1];
  const float* ea = (const float*)d_in[2];
  const int* batch = (const int*)d_in[3];
  const float* W[3]    = {(const float*)d_in[4],  (const float*)d_in[10], (const float*)d_in[16]};
  const float* asrc[3] = {(const float*)d_in[5],  (const float*)d_in[11], (const float*)d_in[17]};
  const float* adst[3] = {(const float*)d_in[6],  (const float*)d_in[12], (const float*)d_in[18]};
  const float* Wep[3]  = {(const float*)d_in[7],  (const float*)d_in[13], (const float*)d_in[19]};
  const float* aep[3]  = {(const float*)d_in[8],  (const float*)d_in[14], (const float*)d_in[20]};
  const float* bp[3]   = {(const float*)d_in[9],  (const float*)d_in[15], (const float*)d_in[21]};

  char* ws = (char*)d_ws;
  size_t off = 0;
  auto take = [&](size_t bytes) -> void* {
    void* p = ws + off;
    off = (off + bytes + 255) & ~(size_t)255;
    return p;
  };
  float* zero_region = (float*)take((16 + 8192 + 64) * 4);
  float* ea_sum = zero_region;
  float* pool   = zero_region + 16;
  float* cnt    = zero_region + 16 + 8192;
  float* wvec    = (float*)take(192 * 4);
  float* ae_self = (float*)take(12 * 4);
  int* deg     = (int*)take((size_t)N_NODES * 4);
  int* offsets = (int*)take(((size_t)N_NODES + 1) * 4);
  int* cursor  = (int*)take((size_t)N_NODES * 4);
  int* csr_src = (int*)take((size_t)(N_EDGES + N_NODES) * 4);
  int* csr_eid = (int*)take((size_t)(N_EDGES + N_NODES) * 4);
  float* a_s  = (float*)take((size_t)N_NODES * NHEADS * 4);   // contiguous with a_d
  float* a_d  = (float*)take((size_t)N_NODES * NHEADS * 4);
  float* a_e  = (float*)take((size_t)3 * N_EDGES * NHEADS * 4);  // all 3 layers
  ushort* Ahi = (ushort*)take((size_t)N_NODES * 256 * 2);
  ushort* Alo = (ushort*)take((size_t)N_NODES * 256 * 2);
  ushort* Bthi = (ushort*)take((size_t)512 * 256 * 2);
  ushort* Btlo = (ushort*)take((size_t)512 * 256 * 2);
  __half* h16 = (__half*)take((size_t)N_NODES * 512 * 2);
  float* ybuf = (float*)take((size_t)N_NODES * 128 * 4);

  const int* srcp = ei;
  const int* dstp = ei + N_EDGES;

  hipMemsetAsync(zero_region, 0, (16 + 8192 + 64) * 4, stream);
  ea_colsum_kernel<<<512, 256, 0, stream>>>(ea, ea_sum, N_EDGES);
  deg_init_kernel<<<(N_NODES + 255) / 256, 256, 0, stream>>>(deg, N_NODES);
  deg_count_kernel<<<2048, 256, 0, stream>>>(dstp, deg, N_EDGES);
  scan_kernel<<<1, 1024, 0, stream>>>(deg, offsets, cursor, N_NODES);
  scatter_kernel<<<2048, 256, 0, stream>>>(srcp, dstp, cursor, csr_src, csr_eid,
                                           N_EDGES, N_NODES);
  wvec_kernel<<<1, 256, 0, stream>>>(Wep[0], aep[0], Wep[1], aep[1], Wep[2], aep[2],
                                     ea_sum, wvec, ae_self);
  ae_all_kernel<<<2048, 256, 0, stream>>>(ea, wvec, a_e, N_EDGES);
  split_kernel<<<2048, 256, 0, stream>>>(x, Ahi, Alo, N_NODES * 128);

  for (int l = 0; l < 3; ++l) {
    int K = (l == 0) ? 128 : 256;
    int kshift = (l == 0) ? 7 : 8;
    int C = (l == 2) ? 128 : 64;
    int HC = NHEADS * C;
    hipMemsetAsync(a_s, 0, (size_t)N_NODES * NHEADS * 4 * 2, stream);
    int nB = HC * K;
    splitT_kernel<<<(nB + 255) / 256, 256, 0, stream>>>(W[l], Bthi, Btlo, kshift, HC, nB);
    gemm_mfma_kernel<<<dim3(HC / 128, (N_NODES + 127) / 128), 256, 0, stream>>>(
        Ahi, Alo, Bthi, Btlo, h16, asrc[l], adst[l], a_s, a_d, N_NODES, K, HC, C);
    if (l < 2)
      agg_kernel<64, 0><<<N_NODES, 256, 0, stream>>>(
          h16, a_s, a_d, a_e + (size_t)l * N_EDGES * NHEADS, ae_self + l * 4, offsets,
          csr_src, csr_eid, bp[l], Ahi, Alo, nullptr);
    else
      agg_kernel<128, 1><<<N_NODES, 256, 0, stream>>>(
          h16, a_s, a_d, a_e + (size_t)l * N_EDGES * NHEADS, ae_self + l * 4, offsets,
          csr_src, csr_eid, bp[l], nullptr, nullptr, ybuf);
  }
  pool_kernel<<<(N_NODES + 255) / 256, 128, 0, stream>>>(ybuf, batch, pool, cnt, N_NODES);
  finalize_kernel<<<(8192 + 255) / 256, 256, 0, stream>>>(pool, cnt, (float*)d_out);
}

// Round 5
// 817.357 us; speedup vs baseline: 1.8034x; 1.1008x over previous
//
#include <hip/hip_runtime.h>
#include <hip/hip_bf16.h>
#include <hip/hip_fp16.h>
#include <math.h>

#define N_NODES 50000
#define N_EDGES 800000
#define NHEADS  4
#define NEG_SLOPE 0.2f

typedef __attribute__((ext_vector_type(8))) _Float16 half8v;
typedef __attribute__((ext_vector_type(4))) float f32x4;

__device__ __forceinline__ void gld_lds16(const ushort* g, ushort* l) {
  __builtin_amdgcn_global_load_lds(
      (const __attribute__((address_space(1))) void*)g,
      (__attribute__((address_space(3))) void*)l, 16, 0, 0);
}

__device__ __forceinline__ void fma4(float4& a, uint2 r, float e) {
  __half2 p = *(__half2*)&r.x, q = *(__half2*)&r.y;
  float2 f = __half22float2(p), g2 = __half22float2(q);
  a.x += e * f.x; a.y += e * f.y; a.z += e * g2.x; a.w += e * g2.y;
}

// ---------------------------------------------------------------------------
// fp32 -> fp16 cast (layer-0 input), 4 elems/thread
// ---------------------------------------------------------------------------
__global__ void tofp16_kernel(const float* __restrict__ in, __half* __restrict__ out,
                              int n4) {
  int i = blockIdx.x * blockDim.x + threadIdx.x;
  if (i >= n4) return;
  float4 v = ((const float4*)in)[i];
  __half2 a = __floats2half2_rn(v.x, v.y);
  __half2 b = __floats2half2_rn(v.z, v.w);
  ((__half2*)out)[2 * i] = a;
  ((__half2*)out)[2 * i + 1] = b;
}

// split + transpose: W[K][N] -> Bth/Btl [N][K] fp16 hi/lo
__global__ void splitT16_kernel(const float* __restrict__ W, __half* __restrict__ hi,
                                __half* __restrict__ lo, int kshift, int N, int n) {
  int i = blockIdx.x * blockDim.x + threadIdx.x;
  if (i >= n) return;
  int K = 1 << kshift;
  int nn = i >> kshift, k = i & (K - 1);
  float v = W[(size_t)k * N + nn];
  __half h = __float2half(v);
  hi[i] = h;
  lo[i] = __float2half(v - __half2float(h));
}

// ---------------------------------------------------------------------------
// fp16 split-B MFMA GEMM, 128x128 tile, BK=32, LDS-staged (24 KB).
// C = Ah*Bh + Ah*Bl (fp32 accum).  Bt is [N][K] fp16 hi/lo.
// Epilogue: h16 (fp16) + a_s/a_d = h . asrc/adst via 16-lane reduce + atomics.
// ---------------------------------------------------------------------------
__global__ __launch_bounds__(256) void gemm_mfma_kernel(
    const __half* __restrict__ Ah, const __half* __restrict__ Bth,
    const __half* __restrict__ Btl, __half* __restrict__ h16,
    const float* __restrict__ asrc, const float* __restrict__ adst,
    float* __restrict__ a_s, float* __restrict__ a_d, int M, int K, int N, int Cph) {
  __shared__ ushort lds[3 * 4096];  // 3 mats x 512 chunks x 16B = 24 KB
  int tid = threadIdx.x;
  int lane = tid & 63, w = tid >> 6;
  int wm = w >> 1, wn = w & 1;
  int r16 = lane & 15, kgrp = lane >> 4;
  int bm = blockIdx.y * 128, bn = blockIdx.x * 128;

  const ushort* gp[6];
#pragma unroll
  for (int i = 0; i < 6; ++i) {
    int c = i * 256 + tid;
    int mmat = c >> 9;
    int s = c & 511;
    int row = s >> 2;
    int kg = (s & 3) ^ ((row >> 1) & 3);  // pre-swizzled source chunk
    const ushort* base;
    int rowg;
    if (mmat == 0)      { base = (const ushort*)Ah;  rowg = min(bm + row, M - 1); }
    else if (mmat == 1) { base = (const ushort*)Bth; rowg = bn + row; }
    else                { base = (const ushort*)Btl; rowg = bn + row; }
    gp[i] = base + (size_t)rowg * K + kg * 8;
  }

  f32x4 acc[4][4] = {};
  for (int k0 = 0; k0 < K; k0 += 32) {
#pragma unroll
    for (int i = 0; i < 6; ++i)
      gld_lds16(gp[i] + k0, lds + i * 2048 + tid * 8);
    __syncthreads();
    half8v ah[4], bh[4], bl[4];
#pragma unroll
    for (int m = 0; m < 4; ++m) {
      int row = wm * 64 + m * 16 + r16;
      int s = row * 4 + (kgrp ^ ((row >> 1) & 3));
      ah[m] = *(const half8v*)(lds + 0 * 4096 + s * 8);
    }
#pragma unroll
    for (int j = 0; j < 4; ++j) {
      int row = wn * 64 + j * 16 + r16;
      int s = row * 4 + (kgrp ^ ((row >> 1) & 3));
      bh[j] = *(const half8v*)(lds + 1 * 4096 + s * 8);
      bl[j] = *(const half8v*)(lds + 2 * 4096 + s * 8);
    }
#pragma unroll
    for (int m = 0; m < 4; ++m)
#pragma unroll
      for (int j = 0; j < 4; ++j) {
        acc[m][j] = __builtin_amdgcn_mfma_f32_16x16x32_f16(ah[m], bh[j], acc[m][j], 0, 0, 0);
        acc[m][j] = __builtin_amdgcn_mfma_f32_16x16x32_f16(ah[m], bl[j], acc[m][j], 0, 0, 0);
      }
    __syncthreads();
  }

  int colbase = bn + wn * 64;
  int hd = colbase / Cph;  // wave-uniform head
#pragma unroll
  for (int m = 0; m < 4; ++m) {
#pragma unroll
    for (int r = 0; r < 4; ++r) {
      int row = bm + wm * 64 + m * 16 + kgrp * 4 + r;
      bool ok = row < M;
      float ps = 0.f, pd = 0.f;
#pragma unroll
      for (int j = 0; j < 4; ++j) {
        float val = acc[m][j][r];
        int col = colbase + 16 * j + r16;
        if (ok) h16[(size_t)row * N + col] = __float2half(val);
        ps += val * asrc[col];
        pd += val * adst[col];
      }
#pragma unroll
      for (int o = 8; o >= 1; o >>= 1) {
        ps += __shfl_xor(ps, o);
        pd += __shfl_xor(pd, o);
      }
      if (r16 == 0 && ok) {
        atomicAdd(&a_s[row * NHEADS + hd], ps);
        atomicAdd(&a_d[row * NHEADS + hd], pd);
      }
    }
  }
}

// ---------------------------------------------------------------------------
// edge_attr column sums (for mean)
// ---------------------------------------------------------------------------
__global__ void ea_colsum_kernel(const float* __restrict__ ea,
                                 float* __restrict__ sums, int E) {
  int tid = threadIdx.x;
  int col = tid & 15;
  float s = 0.f;
  for (int r = blockIdx.x * 16 + (tid >> 4); r < E; r += gridDim.x * 16)
    s += ea[(size_t)r * 16 + col];
  __shared__ float red[256];
  red[tid] = s;
  __syncthreads();
  for (int off = 128; off >= 16; off >>= 1) {
    if (tid < off) red[tid] += red[tid + off];
    __syncthreads();
  }
  if (tid < 16) atomicAdd(&sums[tid], red[tid]);
}

// ---------------------------------------------------------------------------
// wvec[l][k][h] = sum_c We_l[k, h*C+c] * ae_l[h,c];  ae_self[l][h] from mean ea
// ---------------------------------------------------------------------------
__global__ void wvec_kernel(const float* __restrict__ We0, const float* __restrict__ ae0,
                            const float* __restrict__ We1, const float* __restrict__ ae1,
                            const float* __restrict__ We2, const float* __restrict__ ae2,
                            const float* __restrict__ ea_sum,
                            float* __restrict__ wvec, float* __restrict__ ae_self) {
  __shared__ float sw[192];
  int tid = threadIdx.x;
  if (tid < 192) {
    int l = tid >> 6, rem = tid & 63, k = rem >> 2, hd = rem & 3;
    int C = (l == 2) ? 128 : 64;
    const float* We = (l == 0) ? We0 : (l == 1) ? We1 : We2;
    const float* ae = (l == 0) ? ae0 : (l == 1) ? ae1 : ae2;
    float s = 0.f;
    for (int c = 0; c < C; ++c) s += We[(size_t)k * (4 * C) + hd * C + c] * ae[hd * C + c];
    sw[tid] = s;
    wvec[tid] = s;  // layout: l*64 + k*4 + hd
  }
  __syncthreads();
  if (tid < 12) {
    int l = tid >> 2, hd = tid & 3;
    const float invE = 1.0f / (float)N_EDGES;
    float s = 0.f;
    for (int k = 0; k < 16; ++k) s += ea_sum[k] * invE * sw[l * 64 + k * 4 + hd];
    ae_self[tid] = s;
  }
}

// ---------------------------------------------------------------------------
// a_e in CSR order for all 3 layers; self-loop entries pre-filled with ae_self.
// aec[l][p][h] = sum_k ea[csr_eid[p], k] * wv[l,k,h]
// ---------------------------------------------------------------------------
__global__ void ae_csr_kernel(const float* __restrict__ ea, const float* __restrict__ wv,
                              const float* __restrict__ ae_self,
                              const int* __restrict__ csr_eid,
                              float* __restrict__ aec, int tot, int E) {
  int i = blockIdx.x * blockDim.x + threadIdx.x;
  int stride = gridDim.x * blockDim.x;
  for (int p = i; p < tot; p += stride) {
    int eid = csr_eid[p];
    if (eid >= E) {
#pragma unroll
      for (int l = 0; l < 3; ++l)
        *(float4*)(aec + ((size_t)l * tot + p) * 4) =
            make_float4(ae_self[l * 4 + 0], ae_self[l * 4 + 1],
                        ae_self[l * 4 + 2], ae_self[l * 4 + 3]);
    } else {
      float row[16];
      const float4* rp = (const float4*)(ea + (size_t)eid * 16);
#pragma unroll
      for (int q = 0; q < 4; ++q) {
        float4 v = rp[q];
        row[q * 4 + 0] = v.x; row[q * 4 + 1] = v.y;
        row[q * 4 + 2] = v.z; row[q * 4 + 3] = v.w;
      }
#pragma unroll
      for (int l = 0; l < 3; ++l) {
        float s0 = 0, s1 = 0, s2 = 0, s3 = 0;
#pragma unroll
        for (int k = 0; k < 16; ++k) {
          float v = row[k];
          s0 += v * wv[l * 64 + k * 4 + 0];
          s1 += v * wv[l * 64 + k * 4 + 1];
          s2 += v * wv[l * 64 + k * 4 + 2];
          s3 += v * wv[l * 64 + k * 4 + 3];
        }
        *(float4*)(aec + ((size_t)l * tot + p) * 4) = make_float4(s0, s1, s2, s3);
      }
    }
  }
}

// ---------------------------------------------------------------------------
// CSR build
// ---------------------------------------------------------------------------
__global__ void deg_init_kernel(int* deg, int n) {
  int i = blockIdx.x * blockDim.x + threadIdx.x;
  if (i < n) deg[i] = 1;  // self-loop
}
__global__ void deg_count_kernel(const int* __restrict__ dst, int* deg, int E) {
  int i = blockIdx.x * blockDim.x + threadIdx.x;
  int s = gridDim.x * blockDim.x;
  for (; i < E; i += s) atomicAdd(&deg[dst[i]], 1);
}
__global__ void scan_kernel(const int* __restrict__ deg, int* __restrict__ offsets,
                            int* __restrict__ cursor, int n) {
  __shared__ int sums[1024];
  int tid = threadIdx.x;
  int chunk = (n + 1023) >> 10;
  int lo = tid * chunk; if (lo > n) lo = n;
  int hi = lo + chunk;  if (hi > n) hi = n;
  int s = 0;
  for (int i = lo; i < hi; ++i) s += deg[i];
  sums[tid] = s;
  __syncthreads();
  for (int d = 1; d < 1024; d <<= 1) {
    int v = (tid >= d) ? sums[tid - d] : 0;
    __syncthreads();
    sums[tid] += v;
    __syncthreads();
  }
  int run = (tid > 0) ? sums[tid - 1] : 0;
  for (int i = lo; i < hi; ++i) {
    offsets[i] = run;
    cursor[i] = run;
    run += deg[i];
  }
  if (tid == 0) offsets[n] = sums[1023];
}
__global__ void scatter_kernel(const int* __restrict__ src, const int* __restrict__ dst,
                               int* cursor, int* __restrict__ csr_src,
                               int* __restrict__ csr_eid, int E, int n) {
  int i = blockIdx.x * blockDim.x + threadIdx.x;
  int s = gridDim.x * blockDim.x;
  int tot = E + n;
  for (; i < tot; i += s) {
    int ss, dd, eid;
    if (i < E) { ss = src[i]; dd = dst[i]; eid = i; }
    else       { ss = i - E; dd = ss;     eid = E; }   // self-loop sentinel
    int pos = atomicAdd(&cursor[dd], 1);
    csr_src[pos] = ss;
    csr_eid[pos] = eid;
  }
}

// ---------------------------------------------------------------------------
// aggregation: phase 1 (wave=head, lane=edge) softmax -> LDS; phase 2: all
// 256 threads = HC/4 four-half slots x G edge groups, 8B loads, unroll-4.
// a_e is CSR-ordered (self-loops resolved).  MODE 0 -> fp16 y (next A);
// MODE 1 -> head-mean fp32.
// ---------------------------------------------------------------------------
template <int C, int MODE>
__global__ __launch_bounds__(256) void agg_kernel(
    const __half* __restrict__ h, const float* __restrict__ a_s,
    const float* __restrict__ a_d, const float* __restrict__ a_e,
    const int* __restrict__ offsets, const int* __restrict__ csr_src,
    const float* __restrict__ bias, __half* __restrict__ y16,
    float* __restrict__ yf) {
  constexpr int HC = NHEADS * C;   // 256 or 512
  constexpr int SL = HC / 4;       // 4-half slots per row: 64 or 128
  constexpr int G = 256 / SL;      // edge groups: 4 or 2
  constexpr int HSH = (C == 64) ? 4 : 5;  // head = slot >> HSH

  __shared__ float exbuf[NHEADS][64];
  __shared__ int sbuf[64];
  __shared__ float dshare[NHEADS];
  __shared__ float4 cbuf4[(C == 64) ? 192 : 128];

  int node = blockIdx.x;
  int tid = threadIdx.x;
  int hd = tid >> 6, l = tid & 63;
  int beg = offsets[node], end = offsets[node + 1];
  int deg = end - beg;

  float a_dn = a_d[node * NHEADS + hd];

  int i = tid & (SL - 1);
  int g = tid / SL;
  int hh = i >> HSH;
  float4 acc = make_float4(0.f, 0.f, 0.f, 0.f);

  auto alpha_of = [&](int j, int& s_out) -> float {
    int s = csr_src[j];
    float aev = a_e[(size_t)j * NHEADS + hd];
    float v = a_s[s * NHEADS + hd] + a_dn + aev;
    s_out = s;
    return (v > 0.f) ? v : NEG_SLOPE * v;
  };

  auto accum_chunk = [&](int cnt) {
    int t = g;
    for (; t + 3 * G < cnt; t += 4 * G) {
      int s0 = sbuf[t], s1 = sbuf[t + G], s2 = sbuf[t + 2 * G], s3 = sbuf[t + 3 * G];
      float e0 = exbuf[hh][t], e1 = exbuf[hh][t + G];
      float e2 = exbuf[hh][t + 2 * G], e3 = exbuf[hh][t + 3 * G];
      uint2 r0 = *(const uint2*)(h + (size_t)s0 * HC + 4 * i);
      uint2 r1 = *(const uint2*)(h + (size_t)s1 * HC + 4 * i);
      uint2 r2 = *(const uint2*)(h + (size_t)s2 * HC + 4 * i);
      uint2 r3 = *(const uint2*)(h + (size_t)s3 * HC + 4 * i);
      fma4(acc, r0, e0); fma4(acc, r1, e1); fma4(acc, r2, e2); fma4(acc, r3, e3);
    }
    for (; t < cnt; t += G) {
      int s0 = sbuf[t];
      float e0 = exbuf[hh][t];
      uint2 r0 = *(const uint2*)(h + (size_t)s0 * HC + 4 * i);
      fma4(acc, r0, e0);
    }
  };

  if (deg <= 64) {
    int j = beg + l;
    bool valid = j < end;
    int s = 0;
    float al = -1e30f;
    if (valid) al = alpha_of(j, s);
    float m = al;
#pragma unroll
    for (int o = 32; o >= 1; o >>= 1) m = fmaxf(m, __shfl_xor(m, o));
    float ex = valid ? __expf(al - m) : 0.f;
    float dsum = ex;
#pragma unroll
    for (int o = 32; o >= 1; o >>= 1) dsum += __shfl_xor(dsum, o);
    exbuf[hd][l] = ex;
    if (hd == 0) sbuf[l] = s;
    if (l == 0) dshare[hd] = dsum;
    __syncthreads();
    accum_chunk(deg);
  } else {
    float m = -1e30f;
    for (int j0 = beg; j0 < end; j0 += 64) {
      int j = j0 + l;
      if (j < end) {
        int s;
        m = fmaxf(m, alpha_of(j, s));
      }
    }
#pragma unroll
    for (int o = 32; o >= 1; o >>= 1) m = fmaxf(m, __shfl_xor(m, o));
    float dsum = 0.f;
    for (int j0 = beg; j0 < end; j0 += 64) {
      int j = j0 + l;
      int cnt = min(64, end - j0);
      float ex = 0.f;
      int s = 0;
      if (j < end) {
        float al = alpha_of(j, s);
        ex = __expf(al - m);
      }
      dsum += ex;
      __syncthreads();  // protect exbuf/sbuf from previous chunk's readers
      exbuf[hd][l] = ex;
      if (hd == 0) sbuf[l] = s;
      __syncthreads();
      accum_chunk(cnt);
    }
#pragma unroll
    for (int o = 32; o >= 1; o >>= 1) dsum += __shfl_xor(dsum, o);
    if (l == 0) dshare[hd] = dsum;
    __syncthreads();
  }

  // group reduction + epilogue
  if (MODE == 0) {  // G == 4
    if (g > 0) cbuf4[(g - 1) * SL + i] = acc;
    __syncthreads();
    if (g == 0) {
      float4 c1 = cbuf4[i], c2 = cbuf4[SL + i], c3 = cbuf4[2 * SL + i];
      acc.x += c1.x + c2.x + c3.x;
      acc.y += c1.y + c2.y + c3.y;
      acc.z += c1.z + c2.z + c3.z;
      acc.w += c1.w + c2.w + c3.w;
      float inv = 1.f / (dshare[hh] + 1e-16f);
      const float4 bv = *(const float4*)(bias + 4 * i);
      float o0 = acc.x * inv + bv.x, o1 = acc.y * inv + bv.y;
      float o2 = acc.z * inv + bv.z, o3 = acc.w * inv + bv.w;
      o0 = (o0 > 0.f) ? o0 : (__expf(o0) - 1.f);
      o1 = (o1 > 0.f) ? o1 : (__expf(o1) - 1.f);
      o2 = (o2 > 0.f) ? o2 : (__expf(o2) - 1.f);
      o3 = (o3 > 0.f) ? o3 : (__expf(o3) - 1.f);
      __half2 w0 = __floats2half2_rn(o0, o1);
      __half2 w1 = __floats2half2_rn(o2, o3);
      uint2 pk;
      pk.x = *(uint*)&w0;
      pk.y = *(uint*)&w1;
      *(uint2*)(y16 + (size_t)node * HC + 4 * i) = pk;
    }
  } else {  // G == 2, head-mean over 4 heads (slots i, i+32, i+64, i+96)
    if (g == 1) cbuf4[i] = acc;
    __syncthreads();
    if (g == 0) {
      float4 c1 = cbuf4[i];
      float inv = 1.f / (dshare[hh] + 1e-16f);
      acc.x = (acc.x + c1.x) * inv;
      acc.y = (acc.y + c1.y) * inv;
      acc.z = (acc.z + c1.z) * inv;
      acc.w = (acc.w + c1.w) * inv;
    }
    __syncthreads();
    if (g == 0) cbuf4[i] = acc;
    __syncthreads();
    if (tid < 32) {
      float4 s0 = cbuf4[tid], s1 = cbuf4[tid + 32];
      float4 s2 = cbuf4[tid + 64], s3 = cbuf4[tid + 96];
      const float4 bv = *(const float4*)(bias + 4 * tid);
      float4 o;
      o.x = (s0.x + s1.x + s2.x + s3.x) * 0.25f + bv.x;
      o.y = (s0.y + s1.y + s2.y + s3.y) * 0.25f + bv.y;
      o.z = (s0.z + s1.z + s2.z + s3.z) * 0.25f + bv.z;
      o.w = (s0.w + s1.w + s2.w + s3.w) * 0.25f + bv.w;
      *(float4*)(yf + (size_t)node * 128 + 4 * tid) = o;
    }
  }
}

// ---------------------------------------------------------------------------
// global mean pool
// ---------------------------------------------------------------------------
__global__ void pool_kernel(const float* __restrict__ y, const int* __restrict__ batch,
                            float* __restrict__ pool, float* __restrict__ cnt, int n) {
  int n0 = blockIdx.x * 256;
  if (n0 >= n) return;
  int n1 = min(n0 + 256, n);
  int c = threadIdx.x;  // 128 threads
  float accum = 0.f;
  int cur = batch[n0];
  int cn = 0;
  for (int nd = n0; nd < n1; ++nd) {
    int g = batch[nd];
    if (g != cur) {
      atomicAdd(&pool[cur * 128 + c], accum);
      if (c == 0) atomicAdd(&cnt[cur], (float)cn);
      accum = 0.f; cn = 0; cur = g;
    }
    accum += y[(size_t)nd * 128 + c];
    cn++;
  }
  atomicAdd(&pool[cur * 128 + c], accum);
  if (c == 0) atomicAdd(&cnt[cur], (float)cn);
}
__global__ void finalize_kernel(const float* __restrict__ pool,
                                const float* __restrict__ cnt, float* __restrict__ out) {
  int i = blockIdx.x * blockDim.x + threadIdx.x;
  if (i < 64 * 128) out[i] = pool[i] / fmaxf(cnt[i >> 7], 1.f);
}

// ---------------------------------------------------------------------------
extern "C" void kernel_launch(void* const* d_in, const int* in_sizes, int n_in,
                              void* d_out, int out_size, void* d_ws, size_t ws_size,
                              hipStream_t stream) {
  const float* x = (const float*)d_in[0];
  const int* ei = (const int*)d_in[1];
  const float* ea = (const float*)d_in[2];
  const int* batch = (const int*)d_in[3];
  const float* W[3]    = {(const float*)d_in[4],  (const float*)d_in[10], (const float*)d_in[16]};
  const float* asrc[3] = {(const float*)d_in[5],  (const float*)d_in[11], (const float*)d_in[17]};
  const float* adst[3] = {(const float*)d_in[6],  (const float*)d_in[12], (const float*)d_in[18]};
  const float* Wep[3]  = {(const float*)d_in[7],  (const float*)d_in[13], (const float*)d_in[19]};
  const float* aep[3]  = {(const float*)d_in[8],  (const float*)d_in[14], (const float*)d_in[20]};
  const float* bp[3]   = {(const float*)d_in[9],  (const float*)d_in[15], (const float*)d_in[21]};

  char* ws = (char*)d_ws;
  size_t off = 0;
  auto take = [&](size_t bytes) -> void* {
    void* p = ws + off;
    off = (off + bytes + 255) & ~(size_t)255;
    return p;
  };
  const int TOT = N_EDGES + N_NODES;
  float* zero_region = (float*)take((16 + 8192 + 64) * 4);
  float* ea_sum = zero_region;
  float* pool   = zero_region + 16;
  float* cnt    = zero_region + 16 + 8192;
  float* wvec    = (float*)take(192 * 4);
  float* ae_self = (float*)take(12 * 4);
  int* deg     = (int*)take((size_t)N_NODES * 4);
  int* offsets = (int*)take(((size_t)N_NODES + 1) * 4);
  int* cursor  = (int*)take((size_t)N_NODES * 4);
  int* csr_src = (int*)take((size_t)TOT * 4);
  int* csr_eid = (int*)take((size_t)TOT * 4);
  float* a_s  = (float*)take((size_t)N_NODES * NHEADS * 4);   // contiguous with a_d
  float* a_d  = (float*)take((size_t)N_NODES * NHEADS * 4);
  float* aec  = (float*)take((size_t)3 * TOT * NHEADS * 4);   // CSR-ordered, 3 layers
  __half* x16 = (__half*)take((size_t)N_NODES * 128 * 2);
  __half* Bth = (__half*)take((size_t)512 * 256 * 2);
  __half* Btl = (__half*)take((size_t)512 * 256 * 2);
  __half* h16 = (__half*)take((size_t)N_NODES * 512 * 2);
  __half* y16 = (__half*)take((size_t)N_NODES * 256 * 2);
  float* ybuf = (float*)take((size_t)N_NODES * 128 * 4);

  const int* srcp = ei;
  const int* dstp = ei + N_EDGES;

  hipMemsetAsync(zero_region, 0, (16 + 8192 + 64) * 4, stream);
  ea_colsum_kernel<<<512, 256, 0, stream>>>(ea, ea_sum, N_EDGES);
  deg_init_kernel<<<(N_NODES + 255) / 256, 256, 0, stream>>>(deg, N_NODES);
  deg_count_kernel<<<2048, 256, 0, stream>>>(dstp, deg, N_EDGES);
  scan_kernel<<<1, 1024, 0, stream>>>(deg, offsets, cursor, N_NODES);
  scatter_kernel<<<2048, 256, 0, stream>>>(srcp, dstp, cursor, csr_src, csr_eid,
                                           N_EDGES, N_NODES);
  wvec_kernel<<<1, 256, 0, stream>>>(Wep[0], aep[0], Wep[1], aep[1], Wep[2], aep[2],
                                     ea_sum, wvec, ae_self);
  ae_csr_kernel<<<2048, 256, 0, stream>>>(ea, wvec, ae_self, csr_eid, aec, TOT, N_EDGES);
  tofp16_kernel<<<(N_NODES * 128 / 4 + 255) / 256, 256, 0, stream>>>(x, x16,
                                                                     N_NODES * 128 / 4);

  const __half* Acur = x16;
  for (int l = 0; l < 3; ++l) {
    int K = (l == 0) ? 128 : 256;
    int kshift = (l == 0) ? 7 : 8;
    int C = (l == 2) ? 128 : 64;
    int HC = NHEADS * C;
    hipMemsetAsync(a_s, 0, (size_t)N_NODES * NHEADS * 4 * 2, stream);
    int nB = HC * K;
    splitT16_kernel<<<(nB + 255) / 256, 256, 0, stream>>>(W[l], Bth, Btl, kshift, HC, nB);
    gemm_mfma_kernel<<<dim3(HC / 128, (N_NODES + 127) / 128), 256, 0, stream>>>(
        Acur, Bth, Btl, h16, asrc[l], adst[l], a_s, a_d, N_NODES, K, HC, C);
    if (l < 2) {
      agg_kernel<64, 0><<<N_NODES, 256, 0, stream>>>(
          h16, a_s, a_d, aec + (size_t)l * TOT * NHEADS, offsets, csr_src, bp[l],
          y16, nullptr);
      Acur = y16;
    } else {
      agg_kernel<128, 1><<<N_NODES, 256, 0, stream>>>(
          h16, a_s, a_d, aec + (size_t)l * TOT * NHEADS, offsets, csr_src, bp[l],
          nullptr, ybuf);
    }
  }
  pool_kernel<<<(N_NODES + 255) / 256, 128, 0, stream>>>(ybuf, batch, pool, cnt, N_NODES);
  finalize_kernel<<<(8192 + 255) / 256, 256, 0, stream>>>(pool, cnt, (float*)d_out);
}

// Round 6
// 719.142 us; speedup vs baseline: 2.0497x; 1.1366x over previous
//
#include <hip/hip_runtime.h>
#include <hip/hip_bf16.h>
#include <hip/hip_fp16.h>
#include <math.h>

#define N_NODES 50000
#define N_EDGES 800000
#define NHEADS  4
#define NEG_SLOPE 0.2f

typedef __attribute__((ext_vector_type(8))) _Float16 half8v;
typedef __attribute__((ext_vector_type(4))) float f32x4;

__device__ __forceinline__ void gld_lds16(const ushort* g, ushort* l) {
  __builtin_amdgcn_global_load_lds(
      (const __attribute__((address_space(1))) void*)g,
      (__attribute__((address_space(3))) void*)l, 16, 0, 0);
}

__device__ __forceinline__ void fma4(float4& a, uint2 r, float e) {
  __half2 p = *(__half2*)&r.x, q = *(__half2*)&r.y;
  float2 f = __half22float2(p), g2 = __half22float2(q);
  a.x += e * f.x; a.y += e * f.y; a.z += e * g2.x; a.w += e * g2.y;
}

// ---------------------------------------------------------------------------
// fp32 -> fp16 cast (layer-0 input), 4 elems/thread
// ---------------------------------------------------------------------------
__global__ void tofp16_kernel(const float* __restrict__ in, __half* __restrict__ out,
                              int n4) {
  int i = blockIdx.x * blockDim.x + threadIdx.x;
  if (i >= n4) return;
  float4 v = ((const float4*)in)[i];
  __half2 a = __floats2half2_rn(v.x, v.y);
  __half2 b = __floats2half2_rn(v.z, v.w);
  ((__half2*)out)[2 * i] = a;
  ((__half2*)out)[2 * i + 1] = b;
}

// ---------------------------------------------------------------------------
// split+transpose ALL THREE weight matrices: W[K][N] -> Bt hi/lo [N][K] fp16
// L0: 32768 elems (K=128,N=256); L1: 65536 (K=256,N=256); L2: 131072 (K=256,N=512)
// ---------------------------------------------------------------------------
__global__ void splitT_all_kernel(const float* __restrict__ W0,
                                  const float* __restrict__ W1,
                                  const float* __restrict__ W2,
                                  __half* __restrict__ B0h, __half* __restrict__ B0l,
                                  __half* __restrict__ B1h, __half* __restrict__ B1l,
                                  __half* __restrict__ B2h, __half* __restrict__ B2l) {
  int i = blockIdx.x * 256 + threadIdx.x;
  if (i >= 229376) return;
  const float* W;
  __half *bh, *bl;
  int kshift, N, base;
  if (i < 32768)       { W = W0; bh = B0h; bl = B0l; kshift = 7; N = 256; base = 0; }
  else if (i < 98304)  { W = W1; bh = B1h; bl = B1l; kshift = 8; N = 256; base = 32768; }
  else                 { W = W2; bh = B2h; bl = B2l; kshift = 8; N = 512; base = 98304; }
  int j = i - base;
  int K = 1 << kshift;
  int nn = j >> kshift, k = j & (K - 1);
  float v = W[(size_t)k * N + nn];
  __half h = __float2half(v);
  bh[j] = h;
  bl[j] = __float2half(v - __half2float(h));
}

// ---------------------------------------------------------------------------
// fp16 split-B MFMA GEMM, 128x128 tile, BK=32, LDS-staged (24 KB).
// C = Ah*Bh + Ah*Bl (fp32 accum).  Bt is [N][K] fp16 hi/lo.
// Epilogue: h16 (fp16) + a_s/a_d = h . asrc/adst via 16-lane reduce + atomics.
// ---------------------------------------------------------------------------
__global__ __launch_bounds__(256) void gemm_mfma_kernel(
    const __half* __restrict__ Ah, const __half* __restrict__ Bth,
    const __half* __restrict__ Btl, __half* __restrict__ h16,
    const float* __restrict__ asrc, const float* __restrict__ adst,
    float* __restrict__ a_s, float* __restrict__ a_d, int M, int K, int N, int Cph) {
  __shared__ ushort lds[3 * 4096];  // 3 mats x 512 chunks x 16B = 24 KB
  int tid = threadIdx.x;
  int lane = tid & 63, w = tid >> 6;
  int wm = w >> 1, wn = w & 1;
  int r16 = lane & 15, kgrp = lane >> 4;
  int bm = blockIdx.y * 128, bn = blockIdx.x * 128;

  const ushort* gp[6];
#pragma unroll
  for (int i = 0; i < 6; ++i) {
    int c = i * 256 + tid;
    int mmat = c >> 9;
    int s = c & 511;
    int row = s >> 2;
    int kg = (s & 3) ^ ((row >> 1) & 3);  // pre-swizzled source chunk
    const ushort* base;
    int rowg;
    if (mmat == 0)      { base = (const ushort*)Ah;  rowg = min(bm + row, M - 1); }
    else if (mmat == 1) { base = (const ushort*)Bth; rowg = bn + row; }
    else                { base = (const ushort*)Btl; rowg = bn + row; }
    gp[i] = base + (size_t)rowg * K + kg * 8;
  }

  f32x4 acc[4][4] = {};
  for (int k0 = 0; k0 < K; k0 += 32) {
#pragma unroll
    for (int i = 0; i < 6; ++i)
      gld_lds16(gp[i] + k0, lds + i * 2048 + tid * 8);
    __syncthreads();
    half8v ah[4], bh[4], bl[4];
#pragma unroll
    for (int m = 0; m < 4; ++m) {
      int row = wm * 64 + m * 16 + r16;
      int s = row * 4 + (kgrp ^ ((row >> 1) & 3));
      ah[m] = *(const half8v*)(lds + 0 * 4096 + s * 8);
    }
#pragma unroll
    for (int j = 0; j < 4; ++j) {
      int row = wn * 64 + j * 16 + r16;
      int s = row * 4 + (kgrp ^ ((row >> 1) & 3));
      bh[j] = *(const half8v*)(lds + 1 * 4096 + s * 8);
      bl[j] = *(const half8v*)(lds + 2 * 4096 + s * 8);
    }
#pragma unroll
    for (int m = 0; m < 4; ++m)
#pragma unroll
      for (int j = 0; j < 4; ++j) {
        acc[m][j] = __builtin_amdgcn_mfma_f32_16x16x32_f16(ah[m], bh[j], acc[m][j], 0, 0, 0);
        acc[m][j] = __builtin_amdgcn_mfma_f32_16x16x32_f16(ah[m], bl[j], acc[m][j], 0, 0, 0);
      }
    __syncthreads();
  }

  int colbase = bn + wn * 64;
  int hd = colbase / Cph;  // wave-uniform head
#pragma unroll
  for (int m = 0; m < 4; ++m) {
#pragma unroll
    for (int r = 0; r < 4; ++r) {
      int row = bm + wm * 64 + m * 16 + kgrp * 4 + r;
      bool ok = row < M;
      float ps = 0.f, pd = 0.f;
#pragma unroll
      for (int j = 0; j < 4; ++j) {
        float val = acc[m][j][r];
        int col = colbase + 16 * j + r16;
        if (ok) h16[(size_t)row * N + col] = __float2half(val);
        ps += val * asrc[col];
        pd += val * adst[col];
      }
#pragma unroll
      for (int o = 8; o >= 1; o >>= 1) {
        ps += __shfl_xor(ps, o);
        pd += __shfl_xor(pd, o);
      }
      if (r16 == 0 && ok) {
        atomicAdd(&a_s[row * NHEADS + hd], ps);
        atomicAdd(&a_d[row * NHEADS + hd], pd);
      }
    }
  }
}

// ---------------------------------------------------------------------------
// edge_attr column sums (for mean)
// ---------------------------------------------------------------------------
__global__ void ea_colsum_kernel(const float* __restrict__ ea,
                                 float* __restrict__ sums, int E) {
  int tid = threadIdx.x;
  int col = tid & 15;
  float s = 0.f;
  for (int r = blockIdx.x * 16 + (tid >> 4); r < E; r += gridDim.x * 16)
    s += ea[(size_t)r * 16 + col];
  __shared__ float red[256];
  red[tid] = s;
  __syncthreads();
  for (int off = 128; off >= 16; off >>= 1) {
    if (tid < off) red[tid] += red[tid + off];
    __syncthreads();
  }
  if (tid < 16) atomicAdd(&sums[tid], red[tid]);
}

// ---------------------------------------------------------------------------
// wvec[l][k][h] = sum_c We_l[k, h*C+c] * ae_l[h,c];  ae_self[l][h] from mean ea
// ---------------------------------------------------------------------------
__global__ void wvec_kernel(const float* __restrict__ We0, const float* __restrict__ ae0,
                            const float* __restrict__ We1, const float* __restrict__ ae1,
                            const float* __restrict__ We2, const float* __restrict__ ae2,
                            const float* __restrict__ ea_sum,
                            float* __restrict__ wvec, float* __restrict__ ae_self) {
  __shared__ float sw[192];
  int tid = threadIdx.x;
  if (tid < 192) {
    int l = tid >> 6, rem = tid & 63, k = rem >> 2, hd = rem & 3;
    int C = (l == 2) ? 128 : 64;
    const float* We = (l == 0) ? We0 : (l == 1) ? We1 : We2;
    const float* ae = (l == 0) ? ae0 : (l == 1) ? ae1 : ae2;
    float s = 0.f;
    for (int c = 0; c < C; ++c) s += We[(size_t)k * (4 * C) + hd * C + c] * ae[hd * C + c];
    sw[tid] = s;
    wvec[tid] = s;  // layout: l*64 + k*4 + hd
  }
  __syncthreads();
  if (tid < 12) {
    int l = tid >> 2, hd = tid & 3;
    const float invE = 1.0f / (float)N_EDGES;
    float s = 0.f;
    for (int k = 0; k < 16; ++k) s += ea_sum[k] * invE * sw[l * 64 + k * 4 + hd];
    ae_self[tid] = s;
  }
}

// ---------------------------------------------------------------------------
// CSR build: deg count -> hierarchical scan -> packed scatter
// ---------------------------------------------------------------------------
__global__ void deg_count_kernel(const int* __restrict__ dst, int* deg, int E) {
  int i = blockIdx.x * blockDim.x + threadIdx.x;
  int s = gridDim.x * blockDim.x;
  for (; i < E; i += s) atomicAdd(&deg[dst[i]], 1);
}

// per-block exclusive scan of (deg[i]+1); tmp = exclusive-in-block, bsum = block total
__global__ void scan_a_kernel(const int* __restrict__ deg, int* __restrict__ tmp,
                              int* __restrict__ bsum, int n) {
  __shared__ int s[256];
  int i = blockIdx.x * 256 + threadIdx.x;
  int v = (i < n) ? (deg[i] + 1) : 0;  // +1 = self-loop
  s[threadIdx.x] = v;
  __syncthreads();
  for (int d = 1; d < 256; d <<= 1) {
    int t = (threadIdx.x >= d) ? s[threadIdx.x - d] : 0;
    __syncthreads();
    s[threadIdx.x] += t;
    __syncthreads();
  }
  if (i < n) tmp[i] = s[threadIdx.x] - v;
  if (threadIdx.x == 255) bsum[blockIdx.x] = s[255];
}
// single-block exclusive scan of bsum[nb] (nb <= 256)
__global__ void scan_b_kernel(int* bsum, int nb) {
  __shared__ int s[256];
  int v = (threadIdx.x < nb) ? bsum[threadIdx.x] : 0;
  s[threadIdx.x] = v;
  __syncthreads();
  for (int d = 1; d < 256; d <<= 1) {
    int t = (threadIdx.x >= d) ? s[threadIdx.x - d] : 0;
    __syncthreads();
    s[threadIdx.x] += t;
    __syncthreads();
  }
  if (threadIdx.x < nb) bsum[threadIdx.x] = s[threadIdx.x] - v;
}
__global__ void scan_c_kernel(const int* __restrict__ tmp, const int* __restrict__ bsum,
                              int* __restrict__ offsets, int* __restrict__ cursor,
                              int n, int tot) {
  int i = blockIdx.x * 256 + threadIdx.x;
  if (i < n) {
    int o = tmp[i] + bsum[blockIdx.x];
    offsets[i] = o;
    cursor[i] = o;
  }
  if (i == 0) offsets[n] = tot;
}

// packed scatter: one 8B store per edge (src, eid)
__global__ void scatter_kernel(const int* __restrict__ src, const int* __restrict__ dst,
                               int* cursor, uint2* __restrict__ csr_pack, int E, int n) {
  int i = blockIdx.x * blockDim.x + threadIdx.x;
  int s = gridDim.x * blockDim.x;
  int tot = E + n;
  for (; i < tot; i += s) {
    int ss, dd, eid;
    if (i < E) { ss = src[i]; dd = dst[i]; eid = i; }
    else       { ss = i - E; dd = ss;     eid = E; }   // self-loop sentinel
    int pos = atomicAdd(&cursor[dd], 1);
    csr_pack[pos] = make_uint2((uint)ss, (uint)eid);
  }
}

// ---------------------------------------------------------------------------
// a_e in CSR order for all 3 layers + csr_src unpack (sequential pack read).
// ---------------------------------------------------------------------------
__global__ void ae_csr_kernel(const float* __restrict__ ea, const float* __restrict__ wv,
                              const float* __restrict__ ae_self,
                              const uint2* __restrict__ csr_pack,
                              float* __restrict__ aec, int* __restrict__ csr_src,
                              int tot, int E) {
  int i = blockIdx.x * blockDim.x + threadIdx.x;
  int stride = gridDim.x * blockDim.x;
  for (int p = i; p < tot; p += stride) {
    uint2 pk = csr_pack[p];
    int eid = (int)pk.y;
    csr_src[p] = (int)pk.x;
    if (eid >= E) {
#pragma unroll
      for (int l = 0; l < 3; ++l)
        *(float4*)(aec + ((size_t)l * tot + p) * 4) =
            make_float4(ae_self[l * 4 + 0], ae_self[l * 4 + 1],
                        ae_self[l * 4 + 2], ae_self[l * 4 + 3]);
    } else {
      float row[16];
      const float4* rp = (const float4*)(ea + (size_t)eid * 16);
#pragma unroll
      for (int q = 0; q < 4; ++q) {
        float4 v = rp[q];
        row[q * 4 + 0] = v.x; row[q * 4 + 1] = v.y;
        row[q * 4 + 2] = v.z; row[q * 4 + 3] = v.w;
      }
#pragma unroll
      for (int l = 0; l < 3; ++l) {
        float s0 = 0, s1 = 0, s2 = 0, s3 = 0;
#pragma unroll
        for (int k = 0; k < 16; ++k) {
          float v = row[k];
          s0 += v * wv[l * 64 + k * 4 + 0];
          s1 += v * wv[l * 64 + k * 4 + 1];
          s2 += v * wv[l * 64 + k * 4 + 2];
          s3 += v * wv[l * 64 + k * 4 + 3];
        }
        *(float4*)(aec + ((size_t)l * tot + p) * 4) = make_float4(s0, s1, s2, s3);
      }
    }
  }
}

// ---------------------------------------------------------------------------
// aggregation: phase 1 (wave=head, lane=edge) softmax -> LDS; phase 2: all
// 256 threads = HC/4 four-half slots x G edge groups, 8B loads, unroll-4.
// MODE 0 -> fp16 y (next A); MODE 1 -> head-mean fp32.
// ---------------------------------------------------------------------------
template <int C, int MODE>
__global__ __launch_bounds__(256) void agg_kernel(
    const __half* __restrict__ h, const float* __restrict__ a_s,
    const float* __restrict__ a_d, const float* __restrict__ a_e,
    const int* __restrict__ offsets, const int* __restrict__ csr_src,
    const float* __restrict__ bias, __half* __restrict__ y16,
    float* __restrict__ yf) {
  constexpr int HC = NHEADS * C;   // 256 or 512
  constexpr int SL = HC / 4;       // 4-half slots per row: 64 or 128
  constexpr int G = 256 / SL;      // edge groups: 4 or 2
  constexpr int HSH = (C == 64) ? 4 : 5;  // head = slot >> HSH

  __shared__ float exbuf[NHEADS][64];
  __shared__ int sbuf[64];
  __shared__ float dshare[NHEADS];
  __shared__ float4 cbuf4[(C == 64) ? 192 : 128];

  int node = blockIdx.x;
  int tid = threadIdx.x;
  int hd = tid >> 6, l = tid & 63;
  int beg = offsets[node], end = offsets[node + 1];
  int deg = end - beg;

  float a_dn = a_d[node * NHEADS + hd];

  int i = tid & (SL - 1);
  int g = tid / SL;
  int hh = i >> HSH;
  float4 acc = make_float4(0.f, 0.f, 0.f, 0.f);

  auto alpha_of = [&](int j, int& s_out) -> float {
    int s = csr_src[j];
    float aev = a_e[(size_t)j * NHEADS + hd];
    float v = a_s[s * NHEADS + hd] + a_dn + aev;
    s_out = s;
    return (v > 0.f) ? v : NEG_SLOPE * v;
  };

  auto accum_chunk = [&](int cnt) {
    int t = g;
    for (; t + 3 * G < cnt; t += 4 * G) {
      int s0 = sbuf[t], s1 = sbuf[t + G], s2 = sbuf[t + 2 * G], s3 = sbuf[t + 3 * G];
      float e0 = exbuf[hh][t], e1 = exbuf[hh][t + G];
      float e2 = exbuf[hh][t + 2 * G], e3 = exbuf[hh][t + 3 * G];
      uint2 r0 = *(const uint2*)(h + (size_t)s0 * HC + 4 * i);
      uint2 r1 = *(const uint2*)(h + (size_t)s1 * HC + 4 * i);
      uint2 r2 = *(const uint2*)(h + (size_t)s2 * HC + 4 * i);
      uint2 r3 = *(const uint2*)(h + (size_t)s3 * HC + 4 * i);
      fma4(acc, r0, e0); fma4(acc, r1, e1); fma4(acc, r2, e2); fma4(acc, r3, e3);
    }
    for (; t < cnt; t += G) {
      int s0 = sbuf[t];
      float e0 = exbuf[hh][t];
      uint2 r0 = *(const uint2*)(h + (size_t)s0 * HC + 4 * i);
      fma4(acc, r0, e0);
    }
  };

  if (deg <= 64) {
    int j = beg + l;
    bool valid = j < end;
    int s = 0;
    float al = -1e30f;
    if (valid) al = alpha_of(j, s);
    float m = al;
#pragma unroll
    for (int o = 32; o >= 1; o >>= 1) m = fmaxf(m, __shfl_xor(m, o));
    float ex = valid ? __expf(al - m) : 0.f;
    float dsum = ex;
#pragma unroll
    for (int o = 32; o >= 1; o >>= 1) dsum += __shfl_xor(dsum, o);
    exbuf[hd][l] = ex;
    if (hd == 0) sbuf[l] = s;
    if (l == 0) dshare[hd] = dsum;
    __syncthreads();
    accum_chunk(deg);
  } else {
    float m = -1e30f;
    for (int j0 = beg; j0 < end; j0 += 64) {
      int j = j0 + l;
      if (j < end) {
        int s;
        m = fmaxf(m, alpha_of(j, s));
      }
    }
#pragma unroll
    for (int o = 32; o >= 1; o >>= 1) m = fmaxf(m, __shfl_xor(m, o));
    float dsum = 0.f;
    for (int j0 = beg; j0 < end; j0 += 64) {
      int j = j0 + l;
      int cnt = min(64, end - j0);
      float ex = 0.f;
      int s = 0;
      if (j < end) {
        float al = alpha_of(j, s);
        ex = __expf(al - m);
      }
      dsum += ex;
      __syncthreads();  // protect exbuf/sbuf from previous chunk's readers
      exbuf[hd][l] = ex;
      if (hd == 0) sbuf[l] = s;
      __syncthreads();
      accum_chunk(cnt);
    }
#pragma unroll
    for (int o = 32; o >= 1; o >>= 1) dsum += __shfl_xor(dsum, o);
    if (l == 0) dshare[hd] = dsum;
    __syncthreads();
  }

  // group reduction + epilogue
  if (MODE == 0) {  // G == 4
    if (g > 0) cbuf4[(g - 1) * SL + i] = acc;
    __syncthreads();
    if (g == 0) {
      float4 c1 = cbuf4[i], c2 = cbuf4[SL + i], c3 = cbuf4[2 * SL + i];
      acc.x += c1.x + c2.x + c3.x;
      acc.y += c1.y + c2.y + c3.y;
      acc.z += c1.z + c2.z + c3.z;
      acc.w += c1.w + c2.w + c3.w;
      float inv = 1.f / (dshare[hh] + 1e-16f);
      const float4 bv = *(const float4*)(bias + 4 * i);
      float o0 = acc.x * inv + bv.x, o1 = acc.y * inv + bv.y;
      float o2 = acc.z * inv + bv.z, o3 = acc.w * inv + bv.w;
      o0 = (o0 > 0.f) ? o0 : (__expf(o0) - 1.f);
      o1 = (o1 > 0.f) ? o1 : (__expf(o1) - 1.f);
      o2 = (o2 > 0.f) ? o2 : (__expf(o2) - 1.f);
      o3 = (o3 > 0.f) ? o3 : (__expf(o3) - 1.f);
      __half2 w0 = __floats2half2_rn(o0, o1);
      __half2 w1 = __floats2half2_rn(o2, o3);
      uint2 pk;
      pk.x = *(uint*)&w0;
      pk.y = *(uint*)&w1;
      *(uint2*)(y16 + (size_t)node * HC + 4 * i) = pk;
    }
  } else {  // G == 2, head-mean over 4 heads (slots i, i+32, i+64, i+96)
    if (g == 1) cbuf4[i] = acc;
    __syncthreads();
    if (g == 0) {
      float4 c1 = cbuf4[i];
      float inv = 1.f / (dshare[hh] + 1e-16f);
      acc.x = (acc.x + c1.x) * inv;
      acc.y = (acc.y + c1.y) * inv;
      acc.z = (acc.z + c1.z) * inv;
      acc.w = (acc.w + c1.w) * inv;
    }
    __syncthreads();
    if (g == 0) cbuf4[i] = acc;
    __syncthreads();
    if (tid < 32) {
      float4 s0 = cbuf4[tid], s1 = cbuf4[tid + 32];
      float4 s2 = cbuf4[tid + 64], s3 = cbuf4[tid + 96];
      const float4 bv = *(const float4*)(bias + 4 * tid);
      float4 o;
      o.x = (s0.x + s1.x + s2.x + s3.x) * 0.25f + bv.x;
      o.y = (s0.y + s1.y + s2.y + s3.y) * 0.25f + bv.y;
      o.z = (s0.z + s1.z + s2.z + s3.z) * 0.25f + bv.z;
      o.w = (s0.w + s1.w + s2.w + s3.w) * 0.25f + bv.w;
      *(float4*)(yf + (size_t)node * 128 + 4 * tid) = o;
    }
  }
}

// ---------------------------------------------------------------------------
// global mean pool
// ---------------------------------------------------------------------------
__global__ void pool_kernel(const float* __restrict__ y, const int* __restrict__ batch,
                            float* __restrict__ pool, float* __restrict__ cnt, int n) {
  int n0 = blockIdx.x * 256;
  if (n0 >= n) return;
  int n1 = min(n0 + 256, n);
  int c = threadIdx.x;  // 128 threads
  float accum = 0.f;
  int cur = batch[n0];
  int cn = 0;
  for (int nd = n0; nd < n1; ++nd) {
    int g = batch[nd];
    if (g != cur) {
      atomicAdd(&pool[cur * 128 + c], accum);
      if (c == 0) atomicAdd(&cnt[cur], (float)cn);
      accum = 0.f; cn = 0; cur = g;
    }
    accum += y[(size_t)nd * 128 + c];
    cn++;
  }
  atomicAdd(&pool[cur * 128 + c], accum);
  if (c == 0) atomicAdd(&cnt[cur], (float)cn);
}
__global__ void finalize_kernel(const float* __restrict__ pool,
                                const float* __restrict__ cnt, float* __restrict__ out) {
  int i = blockIdx.x * blockDim.x + threadIdx.x;
  if (i < 64 * 128) out[i] = pool[i] / fmaxf(cnt[i >> 7], 1.f);
}

// ---------------------------------------------------------------------------
extern "C" void kernel_launch(void* const* d_in, const int* in_sizes, int n_in,
                              void* d_out, int out_size, void* d_ws, size_t ws_size,
                              hipStream_t stream) {
  const float* x = (const float*)d_in[0];
  const int* ei = (const int*)d_in[1];
  const float* ea = (const float*)d_in[2];
  const int* batch = (const int*)d_in[3];
  const float* W[3]    = {(const float*)d_in[4],  (const float*)d_in[10], (const float*)d_in[16]};
  const float* asrc[3] = {(const float*)d_in[5],  (const float*)d_in[11], (const float*)d_in[17]};
  const float* adst[3] = {(const float*)d_in[6],  (const float*)d_in[12], (const float*)d_in[18]};
  const float* Wep[3]  = {(const float*)d_in[7],  (const float*)d_in[13], (const float*)d_in[19]};
  const float* aep[3]  = {(const float*)d_in[8],  (const float*)d_in[14], (const float*)d_in[20]};
  const float* bp[3]   = {(const float*)d_in[9],  (const float*)d_in[15], (const float*)d_in[21]};

  char* ws = (char*)d_ws;
  size_t off = 0;
  auto take = [&](size_t bytes) -> void* {
    void* p = ws + off;
    off = (off + bytes + 255) & ~(size_t)255;
    return p;
  };
  const int TOT = N_EDGES + N_NODES;
  // ---- contiguous zero-region: ea_sum | pool | cnt | deg | a_sd (one memset) ----
  size_t zero_begin = off;
  float* ea_sum = (float*)take(16 * 4);
  float* pool   = (float*)take(8192 * 4);
  float* cnt    = (float*)take(64 * 4);
  int*   deg    = (int*)take((size_t)N_NODES * 4);
  float* a_sd   = (float*)take((size_t)3 * 2 * N_NODES * NHEADS * 4);  // [l][s/d][N*4]
  size_t zero_bytes = off - zero_begin;

  float* wvec    = (float*)take(192 * 4);
  float* ae_self = (float*)take(12 * 4);
  int* tmp     = (int*)take((size_t)N_NODES * 4);
  int* bsum    = (int*)take(256 * 4);
  int* offsets = (int*)take(((size_t)N_NODES + 1) * 4);
  int* cursor  = (int*)take((size_t)N_NODES * 4);
  uint2* csr_pack = (uint2*)take((size_t)TOT * 8);
  int* csr_src = (int*)take((size_t)TOT * 4);
  float* aec  = (float*)take((size_t)3 * TOT * NHEADS * 4);   // CSR-ordered, 3 layers
  __half* x16 = (__half*)take((size_t)N_NODES * 128 * 2);
  __half* Bh[3], *Bl[3];
  Bh[0] = (__half*)take((size_t)32768 * 2);  Bl[0] = (__half*)take((size_t)32768 * 2);
  Bh[1] = (__half*)take((size_t)65536 * 2);  Bl[1] = (__half*)take((size_t)65536 * 2);
  Bh[2] = (__half*)take((size_t)131072 * 2); Bl[2] = (__half*)take((size_t)131072 * 2);
  __half* h16 = (__half*)take((size_t)N_NODES * 512 * 2);
  __half* y16 = (__half*)take((size_t)N_NODES * 256 * 2);
  float* ybuf = (float*)take((size_t)N_NODES * 128 * 4);

  const int* srcp = ei;
  const int* dstp = ei + N_EDGES;
  const int NB = (N_NODES + 255) / 256;  // 196 scan blocks

  hipMemsetAsync(ws + zero_begin, 0, zero_bytes, stream);
  ea_colsum_kernel<<<512, 256, 0, stream>>>(ea, ea_sum, N_EDGES);
  deg_count_kernel<<<2048, 256, 0, stream>>>(dstp, deg, N_EDGES);
  scan_a_kernel<<<NB, 256, 0, stream>>>(deg, tmp, bsum, N_NODES);
  scan_b_kernel<<<1, 256, 0, stream>>>(bsum, NB);
  scan_c_kernel<<<NB, 256, 0, stream>>>(tmp, bsum, offsets, cursor, N_NODES, TOT);
  scatter_kernel<<<2048, 256, 0, stream>>>(srcp, dstp, cursor, csr_pack, N_EDGES, N_NODES);
  wvec_kernel<<<1, 256, 0, stream>>>(Wep[0], aep[0], Wep[1], aep[1], Wep[2], aep[2],
                                     ea_sum, wvec, ae_self);
  ae_csr_kernel<<<2048, 256, 0, stream>>>(ea, wvec, ae_self, csr_pack, aec, csr_src,
                                          TOT, N_EDGES);
  tofp16_kernel<<<(N_NODES * 128 / 4 + 255) / 256, 256, 0, stream>>>(x, x16,
                                                                     N_NODES * 128 / 4);
  splitT_all_kernel<<<(229376 + 255) / 256, 256, 0, stream>>>(
      W[0], W[1], W[2], Bh[0], Bl[0], Bh[1], Bl[1], Bh[2], Bl[2]);

  const __half* Acur = x16;
  for (int l = 0; l < 3; ++l) {
    int K = (l == 0) ? 128 : 256;
    int C = (l == 2) ? 128 : 64;
    int HC = NHEADS * C;
    float* a_s = a_sd + (size_t)l * 2 * N_NODES * NHEADS;
    float* a_d = a_s + (size_t)N_NODES * NHEADS;
    gemm_mfma_kernel<<<dim3(HC / 128, (N_NODES + 127) / 128), 256, 0, stream>>>(
        Acur, Bh[l], Bl[l], h16, asrc[l], adst[l], a_s, a_d, N_NODES, K, HC, C);
    if (l < 2) {
      agg_kernel<64, 0><<<N_NODES, 256, 0, stream>>>(
          h16, a_s, a_d, aec + (size_t)l * TOT * NHEADS, offsets, csr_src, bp[l],
          y16, nullptr);
      Acur = y16;
    } else {
      agg_kernel<128, 1><<<N_NODES, 256, 0, stream>>>(
          h16, a_s, a_d, aec + (size_t)l * TOT * NHEADS, offsets, csr_src, bp[l],
          nullptr, ybuf);
    }
  }
  pool_kernel<<<NB, 128, 0, stream>>>(ybuf, batch, pool, cnt, N_NODES);
  finalize_kernel<<<(8192 + 255) / 256, 256, 0, stream>>>(pool, cnt, (float*)d_out);
}